// Round 6
// baseline (651.789 us; speedup 1.0000x reference)
//
#include <hip/hip_runtime.h>
#include <hip/hip_fp8.h>
#include <cstdint>

// ---------------------------------------------------------------------------
// Problem constants
// ---------------------------------------------------------------------------
#define Bv   4
#define Nv   1024
#define Cv   1024
#define Hv   16
#define Iv   77
#define IDv  768
#define HDv  64
#define HIDv 4096
#define Sv   (Iv + Nv)      // 1101
#define BIv  (Bv * Iv)      // 308
#define BSv  (Bv * Sv)      // 4404
#define BNv  (Bv * Nv)      // 4096
#define SPADv 1152          // 18*64, zero-padded key dim for V^T

typedef __bf16 bf16x8_t __attribute__((ext_vector_type(8)));
typedef float  f32x4_t  __attribute__((ext_vector_type(4)));
typedef unsigned short us8_t __attribute__((ext_vector_type(8)));
typedef unsigned char  u8x8_t __attribute__((ext_vector_type(8)));

__device__ inline f32x4_t zero4() { f32x4_t z; z[0]=0.f; z[1]=0.f; z[2]=0.f; z[3]=0.f; return z; }

// float -> bf16, round-nearest-even
__device__ inline unsigned short f2bf(float f) {
    unsigned int u = __builtin_bit_cast(unsigned int, f);
    u = (u + 0x7fffu + ((u >> 16) & 1u)) >> 16;
    return (unsigned short)u;
}
__device__ inline float bf2f(unsigned short u) {
    return __builtin_bit_cast(float, ((unsigned int)u) << 16);
}
// float -> fp8 e4m3 (OCP), RNE+sat via HIP type
__device__ inline unsigned char f2fp8(float x) {
    __hip_fp8_e4m3 t(x);
    return (unsigned char)t.__x;
}

__device__ inline float gelu_f(float x) {
    return 0.5f * x * (1.0f + erff(x * 0.70710678118654752440f));
}

// async global(16B/lane) -> LDS  (dest = wave-uniform base + lane*16)
__device__ inline void gload_lds16(const void* g, void* l) {
    __builtin_amdgcn_global_load_lds(
        (__attribute__((address_space(1))) void*)(unsigned long long)g,
        (__attribute__((address_space(3))) void*)(unsigned long long)l,
        16, 0, 0);
}

// ---------------------------------------------------------------------------
// Fused weight convert. bf16 for qkv/proj/ir; fp8(x32, gamma-folded) for MLP.
// order: qkv | proj(*g1) | fc1 | fc2(*g2) | pfc1 | pfc2(*gate) | ir1 | ir2
// ---------------------------------------------------------------------------
__global__ __launch_bounds__(256) void cvt8_kernel(
        const float* s0, const float* s1, const float* s2, const float* s3,
        const float* s4, const float* s5, const float* s6, const float* s7,
        void* d0, void* d1, void* d2, void* d3,
        void* d4, void* d5, void* d6, void* d7,
        const float* g1, const float* g2, const float* gate) {
    long i = (long)blockIdx.x * 256 + threadIdx.x;
    const float* src; void* dst; long off;
    const float* sptr = nullptr; int K4 = 1; float wmul = 1.0f; bool f8 = false;
    if (i < 2097152) {
        if (i < 786432)       { src = s0; dst = d0; off = i; }
        else if (i < 1048576) { src = s1; dst = d1; off = i - 786432;  sptr = g1; K4 = 256; }
        else                  { src = s2; dst = d2; off = i - 1048576; f8 = true; wmul = 32.f; }
    } else if (i < 4194304) {
        if (i < 3145728)      { src = s3; dst = d3; off = i - 2097152; f8 = true; wmul = 32.f; sptr = g2; K4 = 1024; }
        else                  { src = s4; dst = d4; off = i - 3145728; f8 = true; wmul = 32.f; }
    } else {
        if (i < 5242880)      { src = s5; dst = d5; off = i - 4194304; f8 = true; wmul = 32.f; sptr = gate; K4 = 0x7fffffff; }
        else if (i < 5439488) { src = s6; dst = d6; off = i - 5242880; }
        else                  { src = s7; dst = d7; off = i - 5439488; }
    }
    float sc = (sptr ? sptr[(int)(off / K4)] : 1.0f) * wmul;
    float4 v = ((const float4*)src)[off];
    if (f8) {
        uchar4 o = {f2fp8(v.x * sc), f2fp8(v.y * sc), f2fp8(v.z * sc), f2fp8(v.w * sc)};
        ((uchar4*)dst)[off] = o;
    } else {
        ushort4 o = {f2bf(v.x * sc), f2bf(v.y * sc), f2bf(v.z * sc), f2bf(v.w * sc)};
        ((ushort4*)dst)[off] = o;
    }
}

// qkvb=[qb,0,vb]; bfuse=g2*fc2b+gate*pfc2b; projb=g1*projb; bcat=[fc1b,pfc1b]
__global__ __launch_bounds__(256) void bias_prep_kernel(
        const float* __restrict__ qb, const float* __restrict__ vb,
        const float* __restrict__ fc2b, const float* __restrict__ pfc2b,
        const float* __restrict__ projb_in,
        const float* __restrict__ fc1b, const float* __restrict__ pfc1b,
        const float* __restrict__ g1, const float* __restrict__ g2,
        const float* __restrict__ gate,
        float* __restrict__ qkvb, float* __restrict__ bfuse,
        float* __restrict__ projb, float* __restrict__ bcat) {
    int i = blockIdx.x * 256 + threadIdx.x;
    if (i < 3 * Cv) {
        float v = 0.f;
        if (i < Cv) v = qb[i];
        else if (i >= 2 * Cv) v = vb[i - 2 * Cv];
        qkvb[i] = v;
    } else if (i < 4 * Cv) {
        int n = i - 3 * Cv;
        bfuse[n] = g2[n] * fc2b[n] + gate[0] * pfc2b[n];
    } else if (i < 5 * Cv) {
        int n = i - 4 * Cv;
        projb[n] = g1[n] * projb_in[n];
    } else if (i < 13 * Cv) {
        int j = i - 5 * Cv;
        bcat[j] = (j < HIDv) ? fc1b[j] : pfc1b[j - HIDv];
    }
}

// scatter kv rows [BI, C] bf16 into cat rows b*S + i
__global__ __launch_bounds__(256) void scatter_kv_kernel(const unsigned short* __restrict__ kv,
                                                         unsigned short* __restrict__ cat) {
    int r = blockIdx.x;
    int b = r / Iv, i = r % Iv;
    const uint2* src = (const uint2*)(kv + (size_t)r * Cv);
    uint2* dst = (uint2*)(cat + (size_t)(b * Sv + i) * Cv);
    dst[threadIdx.x] = src[threadIdx.x];
}

// ---------------------------------------------------------------------------
// LayerNorm (fp32 in) -> bf16 (F8=0) or fp8 e4m3 (F8=1), one row per block.
// out row index = (r/div)*stride + r%div + off
// ---------------------------------------------------------------------------
template <int F8>
__global__ __launch_bounds__(256) void ln_kernel(const float* __restrict__ in,
                                                 const float* __restrict__ w,
                                                 const float* __restrict__ bvec,
                                                 void* __restrict__ out,
                                                 int cols, float invcols,
                                                 int div_, int stride_, int off_) {
    const int r = blockIdx.x;
    const int tid = threadIdx.x;
    const float* row = in + (size_t)r * cols;
    float s = 0.f, s2 = 0.f;
    for (int c = tid * 4; c < cols; c += 1024) {
        float4 v = *(const float4*)(row + c);
        s  += v.x + v.y + v.z + v.w;
        s2 += v.x * v.x + v.y * v.y + v.z * v.z + v.w * v.w;
    }
#pragma unroll
    for (int o2 = 32; o2 > 0; o2 >>= 1) { s += __shfl_down(s, o2); s2 += __shfl_down(s2, o2); }
    __shared__ float sh[10];
    const int lane = tid & 63, wave = tid >> 6;
    if (lane == 0) { sh[wave] = s; sh[4 + wave] = s2; }
    __syncthreads();
    if (tid == 0) {
        float S1 = sh[0] + sh[1] + sh[2] + sh[3];
        float S2 = sh[4] + sh[5] + sh[6] + sh[7];
        float mean = S1 * invcols;
        float var  = S2 * invcols - mean * mean;
        sh[8] = mean;
        sh[9] = rsqrtf(var + 1e-5f);
    }
    __syncthreads();
    const float mean = sh[8], rstd = sh[9];
    const size_t orow = (size_t)((r / div_) * stride_ + (r % div_) + off_) * cols;
    for (int c = tid * 4; c < cols; c += 1024) {
        float4 v  = *(const float4*)(row + c);
        float4 wv = *(const float4*)(w + c);
        float4 bv = *(const float4*)(bvec + c);
        float o0 = (v.x - mean) * rstd * wv.x + bv.x;
        float o1 = (v.y - mean) * rstd * wv.y + bv.y;
        float o2 = (v.z - mean) * rstd * wv.z + bv.z;
        float o3 = (v.w - mean) * rstd * wv.w + bv.w;
        if constexpr (F8) {
            uchar4 o = {f2fp8(o0), f2fp8(o1), f2fp8(o2), f2fp8(o3)};
            *(uchar4*)((unsigned char*)out + orow + c) = o;
        } else {
            ushort4 o = {f2bf(o0), f2bf(o1), f2bf(o2), f2bf(o3)};
            *(ushort4*)((unsigned short*)out + orow + c) = o;
        }
    }
}

// ---------------------------------------------------------------------------
// bf16 GEMM (128x128, BK=32, dbuf LDS). MODE 0: bf16 out; MODE 1: gelu bf16.
// ---------------------------------------------------------------------------
template <int MODE>
__global__ __launch_bounds__(256) void gemm_bf16_kernel(
        const unsigned short* __restrict__ A,
        const unsigned short* __restrict__ W,
        const float* __restrict__ bias,
        unsigned short* __restrict__ outp,
        int M, int N, int K) {
    __shared__ unsigned short As[2][128 * 32];
    __shared__ unsigned short Bs[2][128 * 32];
    const int tid  = threadIdx.x;
    const int lane = tid & 63;
    const int wave = tid >> 6;
    const int m16  = lane & 15;
    const int g4   = lane >> 4;
    const int n0 = blockIdx.x * 128;
    const int m0 = blockIdx.y * 128;
    const int wm = (wave >> 1) * 64;
    const int wn = (wave & 1) * 64;

    const int r0  = tid >> 2;
    const int cc0 = (tid & 3) * 8;
    int am0 = m0 + r0;       if (am0 > M - 1) am0 = M - 1;
    int am1 = m0 + r0 + 64;  if (am1 > M - 1) am1 = M - 1;
    const unsigned short* agp0 = A + (size_t)am0 * K + cc0;
    const unsigned short* agp1 = A + (size_t)am1 * K + cc0;
    const unsigned short* bgp0 = W + (size_t)(n0 + r0) * K + cc0;
    const unsigned short* bgp1 = W + (size_t)(n0 + r0 + 64) * K + cc0;

    f32x4_t acc[4][4];
#pragma unroll
    for (int a = 0; a < 4; ++a)
#pragma unroll
        for (int bb = 0; bb < 4; ++bb) acc[a][bb] = zero4();

    auto stage = [&](int buf) {
        gload_lds16(agp0, &As[buf][wave * 512]);
        gload_lds16(agp1, &As[buf][2048 + wave * 512]);
        gload_lds16(bgp0, &Bs[buf][wave * 512]);
        gload_lds16(bgp1, &Bs[buf][2048 + wave * 512]);
        agp0 += 32; agp1 += 32; bgp0 += 32; bgp1 += 32;
    };

    stage(0);
    const int NIT = K >> 5;
    for (int it = 0; it < NIT; ++it) {
        const int cur = it & 1;
        __syncthreads();
        if (it + 1 < NIT) stage(cur ^ 1);
        bf16x8_t xf[4], wf[4];
#pragma unroll
        for (int bb = 0; bb < 4; ++bb)
            xf[bb] = *(const bf16x8_t*)&As[cur][(wm + bb * 16 + m16) * 32 + g4 * 8];
#pragma unroll
        for (int a = 0; a < 4; ++a)
            wf[a] = *(const bf16x8_t*)&Bs[cur][(wn + a * 16 + m16) * 32 + g4 * 8];
#pragma unroll
        for (int a = 0; a < 4; ++a)
#pragma unroll
            for (int bb = 0; bb < 4; ++bb)
                acc[a][bb] = __builtin_amdgcn_mfma_f32_16x16x32_bf16(wf[a], xf[bb], acc[a][bb], 0, 0, 0);
    }

#pragma unroll
    for (int a = 0; a < 4; ++a) {
        const int cb = n0 + wn + a * 16 + g4 * 4;
        const float4 bv4 = *(const float4*)(bias + cb);
#pragma unroll
        for (int bb = 0; bb < 4; ++bb) {
            const int r = m0 + wm + bb * 16 + m16;
            if (r < M) {
                const size_t idx = (size_t)r * N + cb;
                const float v0 = acc[a][bb][0] + bv4.x;
                const float v1 = acc[a][bb][1] + bv4.y;
                const float v2 = acc[a][bb][2] + bv4.z;
                const float v3 = acc[a][bb][3] + bv4.w;
                if constexpr (MODE == 0) {
                    ushort4 o = {f2bf(v0), f2bf(v1), f2bf(v2), f2bf(v3)};
                    *(ushort4*)(outp + idx) = o;
                } else {
                    ushort4 o = {f2bf(gelu_f(v0)), f2bf(gelu_f(v1)),
                                 f2bf(gelu_f(v2)), f2bf(gelu_f(v3))};
                    *(ushort4*)(outp + idx) = o;
                }
            }
        }
    }
}

// ---------------------------------------------------------------------------
// bf16 split-K GEMM -> private bf16 partials (proj). As round 4.
// ---------------------------------------------------------------------------
__global__ __launch_bounds__(256) void gemm_splitk_kernel(
        const unsigned short* __restrict__ A1,
        const unsigned short* __restrict__ W1,
        unsigned short* __restrict__ parts,
        int M, int N, int KA, int Kc) {
    __shared__ unsigned short As[2][128 * 32];
    __shared__ unsigned short Bs[2][128 * 32];
    const int tid  = threadIdx.x;
    const int lane = tid & 63;
    const int wave = tid >> 6;
    const int m16  = lane & 15;
    const int g4   = lane >> 4;
    const int n0 = blockIdx.x * 128;
    const int m0 = blockIdx.y * 128;
    const int z  = blockIdx.z;
    const int wm = (wave >> 1) * 64;
    const int wn = (wave & 1) * 64;
    const int k0 = z * Kc;

    const int r0  = tid >> 2;
    const int cc0 = (tid & 3) * 8;
    const unsigned short* agp0 = A1 + (size_t)(m0 + r0) * KA + k0 + cc0;
    const unsigned short* agp1 = A1 + (size_t)(m0 + r0 + 64) * KA + k0 + cc0;
    const unsigned short* bgp0 = W1 + (size_t)(n0 + r0) * KA + k0 + cc0;
    const unsigned short* bgp1 = W1 + (size_t)(n0 + r0 + 64) * KA + k0 + cc0;

    f32x4_t acc[4][4];
#pragma unroll
    for (int a = 0; a < 4; ++a)
#pragma unroll
        for (int bb = 0; bb < 4; ++bb) acc[a][bb] = zero4();

    auto stage = [&](int buf) {
        gload_lds16(agp0, &As[buf][wave * 512]);
        gload_lds16(agp1, &As[buf][2048 + wave * 512]);
        gload_lds16(bgp0, &Bs[buf][wave * 512]);
        gload_lds16(bgp1, &Bs[buf][2048 + wave * 512]);
        agp0 += 32; agp1 += 32; bgp0 += 32; bgp1 += 32;
    };

    stage(0);
    const int NIT = Kc >> 5;
    for (int it = 0; it < NIT; ++it) {
        const int cur = it & 1;
        __syncthreads();
        if (it + 1 < NIT) stage(cur ^ 1);
        bf16x8_t xf[4], wf[4];
#pragma unroll
        for (int bb = 0; bb < 4; ++bb)
            xf[bb] = *(const bf16x8_t*)&As[cur][(wm + bb * 16 + m16) * 32 + g4 * 8];
#pragma unroll
        for (int a = 0; a < 4; ++a)
            wf[a] = *(const bf16x8_t*)&Bs[cur][(wn + a * 16 + m16) * 32 + g4 * 8];
#pragma unroll
        for (int a = 0; a < 4; ++a)
#pragma unroll
            for (int bb = 0; bb < 4; ++bb)
                acc[a][bb] = __builtin_amdgcn_mfma_f32_16x16x32_bf16(wf[a], xf[bb], acc[a][bb], 0, 0, 0);
    }

    unsigned short* pz = parts + (size_t)z * M * N;
#pragma unroll
    for (int a = 0; a < 4; ++a) {
        const int cb = n0 + wn + a * 16 + g4 * 4;
#pragma unroll
        for (int bb = 0; bb < 4; ++bb) {
            const int r = m0 + wm + bb * 16 + m16;
            const size_t idx = (size_t)r * N + cb;
            ushort4 o = {f2bf(acc[a][bb][0]), f2bf(acc[a][bb][1]),
                         f2bf(acc[a][bb][2]), f2bf(acc[a][bb][3])};
            *(ushort4*)(pz + idx) = o;
        }
    }
}

// ---------------------------------------------------------------------------
// fp8 GEMM, BK=64, dbuf LDS (32 KB): out fp8 = fp8( gelu(acc/32 + bias)*16 ).
// A [M,K] fp8, W [N,K] fp8 (pre-scaled x32). Used for fused fc1+pfc1.
// ---------------------------------------------------------------------------
__global__ __launch_bounds__(256) void gemm_fp8_gelu_kernel(
        const unsigned char* __restrict__ A,
        const unsigned char* __restrict__ W,
        const float* __restrict__ bias,
        unsigned char* __restrict__ outp,
        int M, int N, int K) {
    __shared__ unsigned char As[2][128 * 64];
    __shared__ unsigned char Bs[2][128 * 64];
    const int tid  = threadIdx.x;
    const int lane = tid & 63;
    const int wave = tid >> 6;
    const int m16  = lane & 15;
    const int g4   = lane >> 4;
    const int n0 = blockIdx.x * 128;
    const int m0 = blockIdx.y * 128;
    const int wm = (wave >> 1) * 64;
    const int wn = (wave & 1) * 64;

    const int r0  = tid >> 2;          // 4 threads/row (64 B)
    const int cc0 = (tid & 3) * 16;
    const unsigned char* agp0 = A + (size_t)(m0 + r0) * K + cc0;
    const unsigned char* agp1 = A + (size_t)(m0 + r0 + 64) * K + cc0;
    const unsigned char* bgp0 = W + (size_t)(n0 + r0) * K + cc0;
    const unsigned char* bgp1 = W + (size_t)(n0 + r0 + 64) * K + cc0;

    f32x4_t acc[4][4];
#pragma unroll
    for (int a = 0; a < 4; ++a)
#pragma unroll
        for (int bb = 0; bb < 4; ++bb) acc[a][bb] = zero4();

    auto stage = [&](int buf) {
        gload_lds16(agp0, &As[buf][wave * 1024]);
        gload_lds16(agp1, &As[buf][4096 + wave * 1024]);
        gload_lds16(bgp0, &Bs[buf][wave * 1024]);
        gload_lds16(bgp1, &Bs[buf][4096 + wave * 1024]);
        agp0 += 64; agp1 += 64; bgp0 += 64; bgp1 += 64;
    };

    stage(0);
    const int NIT = K >> 6;
    for (int it = 0; it < NIT; ++it) {
        const int cur = it & 1;
        __syncthreads();
        if (it + 1 < NIT) stage(cur ^ 1);
        long xf[4][2], wf[4][2];
#pragma unroll
        for (int bb = 0; bb < 4; ++bb) {
            const int base = (wm + bb * 16 + m16) * 64;
            xf[bb][0] = __builtin_bit_cast(long, *(const u8x8_t*)&As[cur][base + g4 * 8]);
            xf[bb][1] = __builtin_bit_cast(long, *(const u8x8_t*)&As[cur][base + 32 + g4 * 8]);
        }
#pragma unroll
        for (int a = 0; a < 4; ++a) {
            const int base = (wn + a * 16 + m16) * 64;
            wf[a][0] = __builtin_bit_cast(long, *(const u8x8_t*)&Bs[cur][base + g4 * 8]);
            wf[a][1] = __builtin_bit_cast(long, *(const u8x8_t*)&Bs[cur][base + 32 + g4 * 8]);
        }
#pragma unroll
        for (int a = 0; a < 4; ++a)
#pragma unroll
            for (int bb = 0; bb < 4; ++bb) {
                acc[a][bb] = __builtin_amdgcn_mfma_f32_16x16x32_fp8_fp8(wf[a][0], xf[bb][0], acc[a][bb], 0, 0, 0);
                acc[a][bb] = __builtin_amdgcn_mfma_f32_16x16x32_fp8_fp8(wf[a][1], xf[bb][1], acc[a][bb], 0, 0, 0);
            }
    }

#pragma unroll
    for (int a = 0; a < 4; ++a) {
        const int cb = n0 + wn + a * 16 + g4 * 4;
        const float4 bv4 = *(const float4*)(bias + cb);
#pragma unroll
        for (int bb = 0; bb < 4; ++bb) {
            const int r = m0 + wm + bb * 16 + m16;
            const size_t idx = (size_t)r * N + cb;
            uchar4 o = {f2fp8(gelu_f(acc[a][bb][0] * 0.03125f + bv4.x) * 16.f),
                        f2fp8(gelu_f(acc[a][bb][1] * 0.03125f + bv4.y) * 16.f),
                        f2fp8(gelu_f(acc[a][bb][2] * 0.03125f + bv4.z) * 16.f),
                        f2fp8(gelu_f(acc[a][bb][3] * 0.03125f + bv4.w) * 16.f)};
            *(uchar4*)(outp + idx) = o;
        }
    }
}

// ---------------------------------------------------------------------------
// fp8 split-K GEMM -> bf16 partials (acc/512). z<zsplit -> (A1,W1) else (A2,W2).
// Act pre-scaled x16, weights x32 (+gamma folded) -> descale 1/512.
// ---------------------------------------------------------------------------
__global__ __launch_bounds__(256) void gemm_fp8_splitk_kernel(
        const unsigned char* __restrict__ A1,
        const unsigned char* __restrict__ W1,
        const unsigned char* __restrict__ A2,
        const unsigned char* __restrict__ W2,
        unsigned short* __restrict__ parts,
        int M, int N, int lda, int ldw, int Kc, int zsplit) {
    __shared__ unsigned char As[2][128 * 64];
    __shared__ unsigned char Bs[2][128 * 64];
    const int tid  = threadIdx.x;
    const int lane = tid & 63;
    const int wave = tid >> 6;
    const int m16  = lane & 15;
    const int g4   = lane >> 4;
    const int n0 = blockIdx.x * 128;
    const int m0 = blockIdx.y * 128;
    const int z  = blockIdx.z;
    const int wm = (wave >> 1) * 64;
    const int wn = (wave & 1) * 64;

    const unsigned char* A = (z < zsplit) ? A1 : A2;
    const unsigned char* W = (z < zsplit) ? W1 : W2;
    const int k0 = (z % zsplit) * Kc;

    const int r0  = tid >> 2;
    const int cc0 = (tid & 3) * 16;
    const unsigned char* agp0 = A + (size_t)(m0 + r0) * lda + k0 + cc0;
    const unsigned char* agp1 = A + (size_t)(m0 + r0 + 64) * lda + k0 + cc0;
    const unsigned char* bgp0 = W + (size_t)(n0 + r0) * ldw + k0 + cc0;
    const unsigned char* bgp1 = W + (size_t)(n0 + r0 + 64) * ldw + k0 + cc0;

    f32x4_t acc[4][4];
#pragma unroll
    for (int a = 0; a < 4; ++a)
#pragma unroll
        for (int bb = 0; bb < 4; ++bb) acc[a][bb] = zero4();

    auto stage = [&](int buf) {
        gload_lds16(agp0, &As[buf][wave * 1024]);
        gload_lds16(agp1, &As[buf][4096 + wave * 1024]);
        gload_lds16(bgp0, &Bs[buf][wave * 1024]);
        gload_lds16(bgp1, &Bs[buf][4096 + wave * 1024]);
        agp0 += 64; agp1 += 64; bgp0 += 64; bgp1 += 64;
    };

    stage(0);
    const int NIT = Kc >> 6;
    for (int it = 0; it < NIT; ++it) {
        const int cur = it & 1;
        __syncthreads();
        if (it + 1 < NIT) stage(cur ^ 1);
        long xf[4][2], wf[4][2];
#pragma unroll
        for (int bb = 0; bb < 4; ++bb) {
            const int base = (wm + bb * 16 + m16) * 64;
            xf[bb][0] = __builtin_bit_cast(long, *(const u8x8_t*)&As[cur][base + g4 * 8]);
            xf[bb][1] = __builtin_bit_cast(long, *(const u8x8_t*)&As[cur][base + 32 + g4 * 8]);
        }
#pragma unroll
        for (int a = 0; a < 4; ++a) {
            const int base = (wn + a * 16 + m16) * 64;
            wf[a][0] = __builtin_bit_cast(long, *(const u8x8_t*)&Bs[cur][base + g4 * 8]);
            wf[a][1] = __builtin_bit_cast(long, *(const u8x8_t*)&Bs[cur][base + 32 + g4 * 8]);
        }
#pragma unroll
        for (int a = 0; a < 4; ++a)
#pragma unroll
            for (int bb = 0; bb < 4; ++bb) {
                acc[a][bb] = __builtin_amdgcn_mfma_f32_16x16x32_fp8_fp8(wf[a][0], xf[bb][0], acc[a][bb], 0, 0, 0);
                acc[a][bb] = __builtin_amdgcn_mfma_f32_16x16x32_fp8_fp8(wf[a][1], xf[bb][1], acc[a][bb], 0, 0, 0);
            }
    }

    unsigned short* pz = parts + (size_t)z * M * N;
    const float ds = 1.0f / 512.0f;
#pragma unroll
    for (int a = 0; a < 4; ++a) {
        const int cb = n0 + wn + a * 16 + g4 * 4;
#pragma unroll
        for (int bb = 0; bb < 4; ++bb) {
            const int r = m0 + wm + bb * 16 + m16;
            const size_t idx = (size_t)r * N + cb;
            ushort4 o = {f2bf(acc[a][bb][0] * ds), f2bf(acc[a][bb][1] * ds),
                         f2bf(acc[a][bb][2] * ds), f2bf(acc[a][bb][3] * ds)};
            *(ushort4*)(pz + idx) = o;
        }
    }
}

// ---------------------------------------------------------------------------
// Split-K reduce: out[i] = resid[i] + bias[i%N] + sum_z parts[z][i]  (fp32 out)
// ---------------------------------------------------------------------------
template <int NP>
__global__ __launch_bounds__(256) void reduce_kernel(
        const unsigned short* __restrict__ parts,
        const float* __restrict__ resid,
        const float* __restrict__ bias,
        float* __restrict__ out, int MN, int N4mask) {
    int i = blockIdx.x * 256 + threadIdx.x;
    if (i * 4 >= MN) return;
    float4 res = ((const float4*)resid)[i];
    float4 bv  = *(const float4*)(bias + (i & N4mask) * 4);
    float4 o = {res.x + bv.x, res.y + bv.y, res.z + bv.z, res.w + bv.w};
#pragma unroll
    for (int z = 0; z < NP; ++z) {
        ushort4 u = ((const ushort4*)(parts + (size_t)z * MN))[i];
        o.x += bf2f(u.x); o.y += bf2f(u.y); o.z += bf2f(u.z); o.w += bf2f(u.w);
    }
    ((float4*)out)[i] = o;
}

// ---------------------------------------------------------------------------
// V^T pre-transpose with baked PV key-permutation.
// ---------------------------------------------------------------------------
__global__ __launch_bounds__(256) void vtrans_kernel(const unsigned short* __restrict__ qkv,
                                                     unsigned short* __restrict__ vt) {
    __shared__ unsigned short Vs[64 * 64];
    const int stile = blockIdx.x;
    const int bh = blockIdx.y;
    const int b = bh >> 4, h = bh & 15;
    const int tid = threadIdx.x;
#pragma unroll
    for (int j = 0; j < 2; ++j) {
        int c = j * 256 + tid;
        int r = c >> 3, d8 = (c & 7) * 8;
        int s = stile * 64 + r;
        uint4 v = {0u, 0u, 0u, 0u};
        if (s < Sv) v = *(const uint4*)(qkv + ((size_t)(b * Sv + s) * 3 + 2) * Cv + h * 64 + d8);
        *(uint4*)&Vs[r * 64 + d8] = v;
    }
    __syncthreads();
    const int d  = tid >> 2;
    const int p0 = (tid & 3) * 16;
    unsigned short tmp[16];
#pragma unroll
    for (int e = 0; e < 16; ++e) {
        int p = p0 + e;
        int s_local = (p & 32) + 16 * ((p >> 2) & 1) + 4 * ((p & 31) >> 3) + (p & 3);
        tmp[e] = Vs[s_local * 64 + d];
    }
    unsigned short* dst = vt + ((size_t)bh * 64 + d) * SPADv + stile * 64 + p0;
    *(uint4*)dst       = *(const uint4*)&tmp[0];
    *(uint4*)(dst + 8) = *(const uint4*)&tmp[8];
}

// ---------------------------------------------------------------------------
// Flash attention, S^T formulation.
// ---------------------------------------------------------------------------
__global__ __launch_bounds__(256) void attn_kernel(const unsigned short* __restrict__ qkv,
                                                   const unsigned short* __restrict__ vt,
                                                   unsigned short* __restrict__ o) {
    __shared__ unsigned short Qs[64 * 64];
    __shared__ unsigned short Ks[2][64 * 64];
    __shared__ unsigned short Vts[2][64 * 64];

    const int tid  = threadIdx.x;
    const int lane = tid & 63;
    const int wave = tid >> 6;
    const int m16  = lane & 15;
    const int g4   = lane >> 4;
    const int qt = blockIdx.x;
    const int bh = blockIdx.y;
    const int b = bh >> 4, h = bh & 15;

    const int lr = lane >> 3;
    const int csw = ((lane & 7) ^ lr) * 8;
    const int sw7 = m16 & 7;

#pragma unroll
    for (int j = 0; j < 2; ++j) {
        int r = wave * 16 + j * 8 + lr;
        int s = Iv + qt * 64 + r;
        gload_lds16(qkv + ((size_t)(b * Sv + s) * 3) * Cv + h * 64 + csw,
                    &Qs[(wave * 16 + j * 8) * 64]);
    }

    auto stage_kv = [&](int st, int buf) {
#pragma unroll
        for (int j = 0; j < 2; ++j) {
            int r = wave * 16 + j * 8 + lr;
            int s = st * 64 + r; if (s > Sv - 1) s = Sv - 1;
            gload_lds16(qkv + ((size_t)(b * Sv + s) * 3 + 1) * Cv + h * 64 + csw,
                        &Ks[buf][(wave * 16 + j * 8) * 64]);
            gload_lds16(vt + ((size_t)bh * 64 + r) * SPADv + st * 64 + csw,
                        &Vts[buf][(wave * 16 + j * 8) * 64]);
        }
    };

    f32x4_t oacc[4];
#pragma unroll
    for (int dt = 0; dt < 4; ++dt) oacc[dt] = zero4();
    float m_run = -1e30f, l_run = 0.f;

    stage_kv(0, 0);
    __syncthreads();

    const bf16x8_t qf0 = *(const bf16x8_t*)&Qs[(wave * 16 + m16) * 64 + ((g4 ^ sw7) * 8)];
    const bf16x8_t qf1 = *(const bf16x8_t*)&Qs[(wave * 16 + m16) * 64 + (((4 + g4) ^ sw7) * 8)];

    const int NT = (Sv + 63) / 64;   // 18
    for (int st = 0; st < NT; ++st) {
        const int cur = st & 1;
        if (st + 1 < NT) stage_kv(st + 1, cur ^ 1);

        f32x4_t sc[4];
#pragma unroll
        for (int kt = 0; kt < 4; ++kt) {
            bf16x8_t k0 = *(const bf16x8_t*)&Ks[cur][(kt * 16 + m16) * 64 + ((g4 ^ sw7) * 8)];
            bf16x8_t k1 = *(const bf16x8_t*)&Ks[cur][(kt * 16 + m16) * 64 + (((4 + g4) ^ sw7) * 8)];
            f32x4_t z = zero4();
            z = __builtin_amdgcn_mfma_f32_16x16x32_bf16(k0, qf0, z, 0, 0, 0);
            z = __builtin_amdgcn_mfma_f32_16x16x32_bf16(k1, qf1, z, 0, 0, 0);
            sc[kt] = z;
        }

        float mx = -1e30f;
#pragma unroll
        for (int kt = 0; kt < 4; ++kt)
#pragma unroll
            for (int r = 0; r < 4; ++r) {
                int key = st * 64 + kt * 16 + g4 * 4 + r;
                float v = sc[kt][r] * 0.125f;
                v = (key < Sv) ? v : -1e30f;
                sc[kt][r] = v;
                mx = fmaxf(mx, v);
            }
        mx = fmaxf(mx, __shfl_xor(mx, 16));
        mx = fmaxf(mx, __shfl_xor(mx, 32));
        const float mnew  = fmaxf(m_run, mx);
        const float alpha = __expf(m_run - mnew);
        m_run = mnew;
        float sum = 0.f;
#pragma unroll
        for (int kt = 0; kt < 4; ++kt)
#pragma unroll
            for (int r = 0; r < 4; ++r) {
                float p = __expf(sc[kt][r] - mnew);
                sc[kt][r] = p;
                sum += p;
            }
        sum += __shfl_xor(sum, 16);
        sum += __shfl_xor(sum, 32);
        l_run = l_run * alpha + sum;
#pragma unroll
        for (int dt = 0; dt < 4; ++dt) oacc[dt] *= alpha;

        us8_t pu0, pu1;
#pragma unroll
        for (int j = 0; j < 8; ++j) {
            pu0[j] = f2bf(sc[(j >> 2)][j & 3]);
            pu1[j] = f2bf(sc[2 + (j >> 2)][j & 3]);
        }
        const bf16x8_t pf0 = __builtin_bit_cast(bf16x8_t, pu0);
        const bf16x8_t pf1 = __builtin_bit_cast(bf16x8_t, pu1);

#pragma unroll
        for (int dt = 0; dt < 4; ++dt) {
            bf16x8_t v0 = *(const bf16x8_t*)&Vts[cur][(dt * 16 + m16) * 64 + ((g4 ^ sw7) * 8)];
            bf16x8_t v1 = *(const bf16x8_t*)&Vts[cur][(dt * 16 + m16) * 64 + (((4 + g4) ^ sw7) * 8)];
            oacc[dt] = __builtin_amdgcn_mfma_f32_16x16x32_bf16(v0, pf0, oacc[dt], 0, 0, 0);
            oacc[dt] = __builtin_amdgcn_mfma_f32_16x16x32_bf16(v1, pf1, oacc[dt], 0, 0, 0);
        }
        __syncthreads();
    }

    const float inv = 1.0f / l_run;
    const int q = qt * 64 + wave * 16 + m16;
    const size_t row = (size_t)(b * Nv + q) * Cv + h * 64;
#pragma unroll
    for (int dt = 0; dt < 4; ++dt) {
        ushort4 o4 = {f2bf(oacc[dt][0] * inv), f2bf(oacc[dt][1] * inv),
                      f2bf(oacc[dt][2] * inv), f2bf(oacc[dt][3] * inv)};
        *(ushort4*)&o[row + dt * 16 + g4 * 4] = o4;
    }
}

// ---------------------------------------------------------------------------
// Launcher
// ---------------------------------------------------------------------------
extern "C" void kernel_launch(void* const* d_in, const int* in_sizes, int n_in,
                              void* d_out, int out_size, void* d_ws, size_t ws_size,
                              hipStream_t stream) {
    (void)in_sizes; (void)n_in; (void)out_size; (void)ws_size;
    const float* x       = (const float*)d_in[0];
    const float* instr   = (const float*)d_in[1];
    const float* norm1_w = (const float*)d_in[2];
    const float* norm1_b = (const float*)d_in[3];
    const float* qkv_w   = (const float*)d_in[4];
    const float* q_bias  = (const float*)d_in[5];
    const float* v_bias  = (const float*)d_in[6];
    const float* proj_w  = (const float*)d_in[7];
    const float* proj_b  = (const float*)d_in[8];
    const float* gamma_1 = (const float*)d_in[9];
    const float* gamma_2 = (const float*)d_in[10];
    const float* norm2_w = (const float*)d_in[11];
    const float* norm2_b = (const float*)d_in[12];
    const float* fc1_w   = (const float*)d_in[13];
    const float* fc1_b   = (const float*)d_in[14];
    const float* fc2_w   = (const float*)d_in[15];
    const float* fc2_b   = (const float*)d_in[16];
    const float* pfc1_w  = (const float*)d_in[17];
    const float* pfc1_b  = (const float*)d_in[18];
    const float* pfc2_w  = (const float*)d_in[19];
    const float* pfc2_b  = (const float*)d_in[20];
    const float* gate    = (const float*)d_in[21];
    const float* ir_ln_w = (const float*)d_in[22];
    const float* ir_ln_b = (const float*)d_in[23];
    const float* ir_l1_w = (const float*)d_in[24];
    const float* ir_l1_b = (const float*)d_in[25];
    const float* ir_l2_w = (const float*)d_in[26];
    const float* ir_l2_b = (const float*)d_in[27];
    float* out = (float*)d_out;

    char* ws = (char*)d_ws;
    size_t off = 0;
    auto alloc = [&](size_t bytes) -> char* {
        char* p = ws + off;
        off += (bytes + 255) & ~(size_t)255;
        return p;
    };
    unsigned short* w_qkv  = (unsigned short*)alloc((size_t)3 * Cv * Cv * 2);
    unsigned short* w_proj = (unsigned short*)alloc((size_t)Cv * Cv * 2);      // *g1
    unsigned char*  w_mlp1 = (unsigned char*)alloc((size_t)2 * HIDv * Cv);     // fp8: fc1 | pfc1, x32
    unsigned char*  w_fc2  = (unsigned char*)alloc((size_t)Cv * HIDv);         // fp8 *g2*32
    unsigned char*  w_pfc2 = (unsigned char*)alloc((size_t)Cv * HIDv);         // fp8 *gate*32
    unsigned short* w_ir1  = (unsigned short*)alloc((size_t)Cv * IDv * 2);
    unsigned short* w_ir2  = (unsigned short*)alloc((size_t)Cv * Cv * 2);
    float*          qkvb   = (float*)alloc((size_t)3 * Cv * 4);
    float*          bfuse  = (float*)alloc((size_t)Cv * 4);
    float*          projb  = (float*)alloc((size_t)Cv * 4);
    float*          bcat   = (float*)alloc((size_t)2 * HIDv * 4);
    unsigned short* irln   = (unsigned short*)alloc((size_t)BIv * IDv * 2);
    unsigned short* h1     = (unsigned short*)alloc((size_t)BIv * Cv * 2);
    unsigned short* kvtmp  = (unsigned short*)alloc((size_t)BIv * Cv * 2);
    unsigned short* cat    = (unsigned short*)alloc((size_t)BSv * Cv * 2);      // 9.0 MB
    unsigned short* qkvbuf = (unsigned short*)alloc((size_t)BSv * 3 * Cv * 2);  // 27.1 MB
    unsigned short* obuf   = (unsigned short*)alloc((size_t)BNv * Cv * 2);
    float*          x1     = (float*)alloc((size_t)BNv * Cv * 4);
    unsigned char*  ybuf8  = (unsigned char*)alloc((size_t)BNv * Cv);           // fp8
    unsigned char*  gbufA  = (unsigned char*)alloc((size_t)BNv * 2 * HIDv);     // fp8 33.6 MB
    unsigned short* fpart  = (unsigned short*)alloc((size_t)4 * BNv * Cv * 2);  // 33.6 MB
    unsigned short* vt     = (unsigned short*)gbufA;  // vt dead before fc1 writes gbufA
    unsigned short* ppart  = cat;                     // cat+qkvbuf dead after attn

    cvt8_kernel<<<22272, 256, 0, stream>>>(qkv_w, proj_w, fc1_w, fc2_w, pfc1_w, pfc2_w,
                                           ir_l1_w, ir_l2_w,
                                           w_qkv, w_proj, w_mlp1, w_fc2,
                                           w_mlp1 + (size_t)HIDv * Cv, w_pfc2,
                                           w_ir1, w_ir2,
                                           gamma_1, gamma_2, gate);

    bias_prep_kernel<<<52, 256, 0, stream>>>(q_bias, v_bias, fc2_b, pfc2_b, proj_b,
                                             fc1_b, pfc1_b,
                                             gamma_1, gamma_2, gate,
                                             qkvb, bfuse, projb, bcat);

    // instruct branch: LN -> Linear+GELU -> Linear
    ln_kernel<0><<<BIv, 256, 0, stream>>>(instr, ir_ln_w, ir_ln_b, irln,
                                          IDv, 1.0f / IDv, 1 << 28, 0, 0);
    // LN1 writes directly into cat rows b*S + I + n
    ln_kernel<0><<<BNv, 256, 0, stream>>>(x, norm1_w, norm1_b, cat,
                                          Cv, 1.0f / Cv, Nv, Sv, Iv);
    gemm_bf16_kernel<1><<<dim3(Cv / 128, (BIv + 127) / 128), 256, 0, stream>>>(
        irln, w_ir1, ir_l1_b, h1, BIv, Cv, IDv);
    gemm_bf16_kernel<0><<<dim3(Cv / 128, (BIv + 127) / 128), 256, 0, stream>>>(
        h1, w_ir2, ir_l2_b, kvtmp, BIv, Cv, Cv);
    scatter_kv_kernel<<<BIv, 256, 0, stream>>>(kvtmp, cat);

    // QKV projection over cat [BS, C] -> [BS, 3C]
    gemm_bf16_kernel<0><<<dim3(3 * Cv / 128, (BSv + 127) / 128), 256, 0, stream>>>(
        cat, w_qkv, qkvb, qkvbuf, BSv, 3 * Cv, Cv);

    // V^T pre-transpose (permuted), then attention
    vtrans_kernel<<<dim3(18, Bv * Hv), 256, 0, stream>>>(qkvbuf, vt);
    attn_kernel<<<dim3(Nv / 64, Bv * Hv), 256, 0, stream>>>(qkvbuf, vt, obuf);

    // proj split-K=4 (bf16 partials), reduce: x1 = x + g1*proj_b + sum(parts)
    gemm_splitk_kernel<<<dim3(Cv / 128, BNv / 128, 4), 256, 0, stream>>>(
        obuf, w_proj, ppart, BNv, Cv, Cv, Cv / 4);
    reduce_kernel<4><<<(BNv * Cv / 4 + 255) / 256, 256, 0, stream>>>(
        ppart, x, projb, x1, BNv * Cv, Cv / 4 - 1);

    // LN2 -> fp8 activations
    ln_kernel<1><<<BNv, 256, 0, stream>>>(x1, norm2_w, norm2_b, ybuf8,
                                          Cv, 1.0f / Cv, 1 << 28, 0, 0);

    // fused fc1+pfc1 (fp8, N=8192): gbufA = fp8(16*gelu(y@Wcat^T + bcat))
    gemm_fp8_gelu_kernel<<<dim3(2 * HIDv / 128, BNv / 128), 256, 0, stream>>>(
        ybuf8, w_mlp1, bcat, gbufA, BNv, 2 * HIDv, Cv);

    // fc2 + pfc2 fp8 split-K (z=0,1 -> fc2 halves; z=2,3 -> pfc2 halves)
    gemm_fp8_splitk_kernel<<<dim3(Cv / 128, BNv / 128, 4), 256, 0, stream>>>(
        gbufA, w_fc2, gbufA + HIDv, w_pfc2, fpart,
        BNv, Cv, 2 * HIDv, HIDv, HIDv / 2, 2);
    // out = x1 + (g2*fc2_b + gate*pfc2_b) + sum(parts)
    reduce_kernel<4><<<(BNv * Cv / 4 + 255) / 256, 256, 0, stream>>>(
        fpart, x1, bfuse, out, BNv * Cv, Cv / 4 - 1);
}

// Round 7
// 568.622 us; speedup vs baseline: 1.1463x; 1.1463x over previous
//
#include <hip/hip_runtime.h>
#include <cstdint>

// ---------------------------------------------------------------------------
// Problem constants
// ---------------------------------------------------------------------------
#define Bv   4
#define Nv   1024
#define Cv   1024
#define Hv   16
#define Iv   77
#define IDv  768
#define HDv  64
#define HIDv 4096
#define Sv   (Iv + Nv)      // 1101
#define BIv  (Bv * Iv)      // 308
#define BSv  (Bv * Sv)      // 4404
#define BNv  (Bv * Nv)      // 4096
#define SPADv 1152          // 18*64, zero-padded key dim for V^T

typedef __bf16 bf16x8_t __attribute__((ext_vector_type(8)));
typedef float  f32x4_t  __attribute__((ext_vector_type(4)));
typedef unsigned short us8_t __attribute__((ext_vector_type(8)));
typedef long  l2_t  __attribute__((ext_vector_type(2)));

__device__ inline f32x4_t zero4() { f32x4_t z; z[0]=0.f; z[1]=0.f; z[2]=0.f; z[3]=0.f; return z; }

// float -> bf16, round-nearest-even
__device__ inline unsigned short f2bf(float f) {
    unsigned int u = __builtin_bit_cast(unsigned int, f);
    u = (u + 0x7fffu + ((u >> 16) & 1u)) >> 16;
    return (unsigned short)u;
}
__device__ inline float bf2f(unsigned short u) {
    return __builtin_bit_cast(float, ((unsigned int)u) << 16);
}
// 4 floats -> packed fp8 e4m3 (HW convert, RNE sat)
__device__ inline unsigned int f4_fp8(float a, float b, float c, float d) {
    int v = __builtin_amdgcn_cvt_pk_fp8_f32(a, b, 0, false);
    v = __builtin_amdgcn_cvt_pk_fp8_f32(c, d, v, true);
    return (unsigned int)v;
}

__device__ inline float gelu_f(float x) {
    return 0.5f * x * (1.0f + erff(x * 0.70710678118654752440f));
}

// async global(16B/lane) -> LDS  (dest = wave-uniform base + lane*16)
__device__ inline void gload_lds16(const void* g, void* l) {
    __builtin_amdgcn_global_load_lds(
        (__attribute__((address_space(1))) void*)(unsigned long long)g,
        (__attribute__((address_space(3))) void*)(unsigned long long)l,
        16, 0, 0);
}

// ---------------------------------------------------------------------------
// Fused weight convert. bf16 for qkv/proj/fc1/pfc1/ir; fp8(x32, gamma-folded)
// for fc2/pfc2.  uint4 granules.
// order: qkv | proj(*g1) | fc1 | fc2(*g2) | pfc1 | pfc2(*gate) | ir1 | ir2
// ---------------------------------------------------------------------------
__global__ __launch_bounds__(256) void cvt8_kernel(
        const float* s0, const float* s1, const float* s2, const float* s3,
        const float* s4, const float* s5, const float* s6, const float* s7,
        void* d0, void* d1, void* d2, void* d3,
        void* d4, void* d5, void* d6, void* d7,
        const float* g1, const float* g2, const float* gate) {
    long i = (long)blockIdx.x * 256 + threadIdx.x;
    const float* src; void* dst; long off;
    const float* sptr = nullptr; int K4 = 1; float wmul = 1.0f; bool f8 = false;
    if (i < 2097152) {
        if (i < 786432)       { src = s0; dst = d0; off = i; }
        else if (i < 1048576) { src = s1; dst = d1; off = i - 786432;  sptr = g1; K4 = 256; }
        else                  { src = s2; dst = d2; off = i - 1048576; }
    } else if (i < 4194304) {
        if (i < 3145728)      { src = s3; dst = d3; off = i - 2097152; f8 = true; wmul = 32.f; sptr = g2; K4 = 1024; }
        else                  { src = s4; dst = d4; off = i - 3145728; }
    } else {
        if (i < 5242880)      { src = s5; dst = d5; off = i - 4194304; f8 = true; wmul = 32.f; sptr = gate; K4 = 0x7fffffff; }
        else if (i < 5439488) { src = s6; dst = d6; off = i - 5242880; }
        else                  { src = s7; dst = d7; off = i - 5439488; }
    }
    float sc = (sptr ? sptr[(int)(off / K4)] : 1.0f) * wmul;
    float4 v = ((const float4*)src)[off];
    if (f8) {
        ((unsigned int*)dst)[off] = f4_fp8(v.x * sc, v.y * sc, v.z * sc, v.w * sc);
    } else {
        ushort4 o = {f2bf(v.x * sc), f2bf(v.y * sc), f2bf(v.z * sc), f2bf(v.w * sc)};
        ((ushort4*)dst)[off] = o;
    }
}

// qkvb = [q_bias, 0, v_bias]; bfuse = g2*fc2_b + gate*pfc2_b; projb = g1*proj_b
__global__ __launch_bounds__(256) void bias_prep_kernel(
        const float* __restrict__ qb, const float* __restrict__ vb,
        const float* __restrict__ fc2b, const float* __restrict__ pfc2b,
        const float* __restrict__ projb_in,
        const float* __restrict__ g1, const float* __restrict__ g2,
        const float* __restrict__ gate,
        float* __restrict__ qkvb, float* __restrict__ bfuse,
        float* __restrict__ projb) {
    int i = blockIdx.x * 256 + threadIdx.x;
    if (i < 3 * Cv) {
        float v = 0.f;
        if (i < Cv) v = qb[i];
        else if (i >= 2 * Cv) v = vb[i - 2 * Cv];
        qkvb[i] = v;
    } else if (i < 4 * Cv) {
        int n = i - 3 * Cv;
        bfuse[n] = g2[n] * fc2b[n] + gate[0] * pfc2b[n];
    } else if (i < 5 * Cv) {
        int n = i - 4 * Cv;
        projb[n] = g1[n] * projb_in[n];
    }
}

// scatter kv rows [BI, C] bf16 into cat rows b*S + i
__global__ __launch_bounds__(256) void scatter_kv_kernel(const unsigned short* __restrict__ kv,
                                                         unsigned short* __restrict__ cat) {
    int r = blockIdx.x;
    int b = r / Iv, i = r % Iv;
    const uint2* src = (const uint2*)(kv + (size_t)r * Cv);
    uint2* dst = (uint2*)(cat + (size_t)(b * Sv + i) * Cv);
    dst[threadIdx.x] = src[threadIdx.x];
}

// ---------------------------------------------------------------------------
// LayerNorm (fp32 in) -> bf16 out, one row per block.
// out row index = (r/div)*stride + r%div + off
// ---------------------------------------------------------------------------
__global__ __launch_bounds__(256) void ln_kernel(const float* __restrict__ in,
                                                 const float* __restrict__ w,
                                                 const float* __restrict__ bvec,
                                                 unsigned short* __restrict__ out,
                                                 int cols, float invcols,
                                                 int div_, int stride_, int off_) {
    const int r = blockIdx.x;
    const int tid = threadIdx.x;
    const float* row = in + (size_t)r * cols;
    float s = 0.f, s2 = 0.f;
    for (int c = tid * 4; c < cols; c += 1024) {
        float4 v = *(const float4*)(row + c);
        s  += v.x + v.y + v.z + v.w;
        s2 += v.x * v.x + v.y * v.y + v.z * v.z + v.w * v.w;
    }
#pragma unroll
    for (int o2 = 32; o2 > 0; o2 >>= 1) { s += __shfl_down(s, o2); s2 += __shfl_down(s2, o2); }
    __shared__ float sh[10];
    const int lane = tid & 63, wave = tid >> 6;
    if (lane == 0) { sh[wave] = s; sh[4 + wave] = s2; }
    __syncthreads();
    if (tid == 0) {
        float S1 = sh[0] + sh[1] + sh[2] + sh[3];
        float S2 = sh[4] + sh[5] + sh[6] + sh[7];
        float mean = S1 * invcols;
        float var  = S2 * invcols - mean * mean;
        sh[8] = mean;
        sh[9] = rsqrtf(var + 1e-5f);
    }
    __syncthreads();
    const float mean = sh[8], rstd = sh[9];
    unsigned short* orow = out + (size_t)((r / div_) * stride_ + (r % div_) + off_) * cols;
    for (int c = tid * 4; c < cols; c += 1024) {
        float4 v  = *(const float4*)(row + c);
        float4 wv = *(const float4*)(w + c);
        float4 bv = *(const float4*)(bvec + c);
        ushort4 o;
        o.x = f2bf((v.x - mean) * rstd * wv.x + bv.x);
        o.y = f2bf((v.y - mean) * rstd * wv.y + bv.y);
        o.z = f2bf((v.z - mean) * rstd * wv.z + bv.z);
        o.w = f2bf((v.w - mean) * rstd * wv.w + bv.w);
        *(ushort4*)(orow + c) = o;
    }
}

// ---------------------------------------------------------------------------
// bf16 GEMM (128x128, BK=32, dbuf LDS).
// MODE 0: bf16 out    MODE 1: gelu bf16 out
// MODE 2: fp8 out = fp8( gelu(v) * 16 )  (for feeding fp8 fc2)
// SWZ 1: 1D grid (1024), XCD-partitioned m-tiles (M=4096, N-tiles = grid/32).
// Output row stride = ldo elems (fp8: bytes), column offset coff.
// ---------------------------------------------------------------------------
template <int MODE, int SWZ>
__global__ __launch_bounds__(256) void gemm_bf16_kernel(
        const unsigned short* __restrict__ A,
        const unsigned short* __restrict__ W,
        const float* __restrict__ bias,
        void* __restrict__ outp,
        int M, int N, int K, int ldo, int coff) {
    __shared__ unsigned short As[2][128 * 32];
    __shared__ unsigned short Bs[2][128 * 32];
    const int tid  = threadIdx.x;
    const int lane = tid & 63;
    const int wave = tid >> 6;
    const int m16  = lane & 15;
    const int g4   = lane >> 4;
    int bx, by;
    if (SWZ) {
        const int bid = blockIdx.x;
        const int xcd = bid & 7, l = bid >> 3;
        by = (xcd << 2) | (l & 3);   // m-tile: 4 per XCD
        bx = l >> 2;                 // n-tile
    } else { bx = blockIdx.x; by = blockIdx.y; }
    const int n0 = bx * 128;
    const int m0 = by * 128;
    const int wm = (wave >> 1) * 64;
    const int wn = (wave & 1) * 64;

    const int r0  = tid >> 2;
    const int cc0 = (tid & 3) * 8;
    int am0 = m0 + r0;       if (am0 > M - 1) am0 = M - 1;
    int am1 = m0 + r0 + 64;  if (am1 > M - 1) am1 = M - 1;
    const unsigned short* agp0 = A + (size_t)am0 * K + cc0;
    const unsigned short* agp1 = A + (size_t)am1 * K + cc0;
    const unsigned short* bgp0 = W + (size_t)(n0 + r0) * K + cc0;
    const unsigned short* bgp1 = W + (size_t)(n0 + r0 + 64) * K + cc0;

    f32x4_t acc[4][4];
#pragma unroll
    for (int a = 0; a < 4; ++a)
#pragma unroll
        for (int bb = 0; bb < 4; ++bb) acc[a][bb] = zero4();

    auto stage = [&](int buf) {
        gload_lds16(agp0, &As[buf][wave * 512]);
        gload_lds16(agp1, &As[buf][2048 + wave * 512]);
        gload_lds16(bgp0, &Bs[buf][wave * 512]);
        gload_lds16(bgp1, &Bs[buf][2048 + wave * 512]);
        agp0 += 32; agp1 += 32; bgp0 += 32; bgp1 += 32;
    };

    stage(0);
    const int NIT = K >> 5;
    for (int it = 0; it < NIT; ++it) {
        const int cur = it & 1;
        __syncthreads();
        if (it + 1 < NIT) stage(cur ^ 1);
        bf16x8_t xf[4], wf[4];
#pragma unroll
        for (int bb = 0; bb < 4; ++bb)
            xf[bb] = *(const bf16x8_t*)&As[cur][(wm + bb * 16 + m16) * 32 + g4 * 8];
#pragma unroll
        for (int a = 0; a < 4; ++a)
            wf[a] = *(const bf16x8_t*)&Bs[cur][(wn + a * 16 + m16) * 32 + g4 * 8];
#pragma unroll
        for (int a = 0; a < 4; ++a)
#pragma unroll
            for (int bb = 0; bb < 4; ++bb)
                acc[a][bb] = __builtin_amdgcn_mfma_f32_16x16x32_bf16(wf[a], xf[bb], acc[a][bb], 0, 0, 0);
    }

#pragma unroll
    for (int a = 0; a < 4; ++a) {
        const int cb = n0 + wn + a * 16 + g4 * 4;
        const float4 bv4 = *(const float4*)(bias + cb);
#pragma unroll
        for (int bb = 0; bb < 4; ++bb) {
            const int r = m0 + wm + bb * 16 + m16;
            if (r < M) {
                const float v0 = acc[a][bb][0] + bv4.x;
                const float v1 = acc[a][bb][1] + bv4.y;
                const float v2 = acc[a][bb][2] + bv4.z;
                const float v3 = acc[a][bb][3] + bv4.w;
                if constexpr (MODE == 0) {
                    ushort4 o = {f2bf(v0), f2bf(v1), f2bf(v2), f2bf(v3)};
                    *(ushort4*)((unsigned short*)outp + (size_t)r * ldo + cb) = o;
                } else if constexpr (MODE == 1) {
                    ushort4 o = {f2bf(gelu_f(v0)), f2bf(gelu_f(v1)),
                                 f2bf(gelu_f(v2)), f2bf(gelu_f(v3))};
                    *(ushort4*)((unsigned short*)outp + (size_t)r * ldo + cb) = o;
                } else {
                    unsigned int pk = f4_fp8(gelu_f(v0) * 16.f, gelu_f(v1) * 16.f,
                                             gelu_f(v2) * 16.f, gelu_f(v3) * 16.f);
                    *(unsigned int*)((unsigned char*)outp + (size_t)r * ldo + coff + cb) = pk;
                }
            }
        }
    }
}

// ---------------------------------------------------------------------------
// bf16 split-K GEMM -> private bf16 partials (proj).
// 1D grid 1024, XCD-swizzled: m-tiles partitioned per XCD. N=1024(8 nt), z=4.
// ---------------------------------------------------------------------------
__global__ __launch_bounds__(256) void gemm_splitk_kernel(
        const unsigned short* __restrict__ A1,
        const unsigned short* __restrict__ W1,
        unsigned short* __restrict__ parts,
        int M, int N, int KA, int Kc) {
    __shared__ unsigned short As[2][128 * 32];
    __shared__ unsigned short Bs[2][128 * 32];
    const int tid  = threadIdx.x;
    const int lane = tid & 63;
    const int wave = tid >> 6;
    const int m16  = lane & 15;
    const int g4   = lane >> 4;
    const int bid = blockIdx.x;
    const int xcd = bid & 7, l = bid >> 3;
    const int by = (xcd << 2) | (l & 3);   // m-tile (32)
    const int rr = l >> 2;
    const int bx = rr & 7;                 // n-tile (8)
    const int z  = rr >> 3;                // k-split (4)
    const int n0 = bx * 128;
    const int m0 = by * 128;
    const int wm = (wave >> 1) * 64;
    const int wn = (wave & 1) * 64;
    const int k0 = z * Kc;

    const int r0  = tid >> 2;
    const int cc0 = (tid & 3) * 8;
    const unsigned short* agp0 = A1 + (size_t)(m0 + r0) * KA + k0 + cc0;
    const unsigned short* agp1 = A1 + (size_t)(m0 + r0 + 64) * KA + k0 + cc0;
    const unsigned short* bgp0 = W1 + (size_t)(n0 + r0) * KA + k0 + cc0;
    const unsigned short* bgp1 = W1 + (size_t)(n0 + r0 + 64) * KA + k0 + cc0;

    f32x4_t acc[4][4];
#pragma unroll
    for (int a = 0; a < 4; ++a)
#pragma unroll
        for (int bb = 0; bb < 4; ++bb) acc[a][bb] = zero4();

    auto stage = [&](int buf) {
        gload_lds16(agp0, &As[buf][wave * 512]);
        gload_lds16(agp1, &As[buf][2048 + wave * 512]);
        gload_lds16(bgp0, &Bs[buf][wave * 512]);
        gload_lds16(bgp1, &Bs[buf][2048 + wave * 512]);
        agp0 += 32; agp1 += 32; bgp0 += 32; bgp1 += 32;
    };

    stage(0);
    const int NIT = Kc >> 5;
    for (int it = 0; it < NIT; ++it) {
        const int cur = it & 1;
        __syncthreads();
        if (it + 1 < NIT) stage(cur ^ 1);
        bf16x8_t xf[4], wf[4];
#pragma unroll
        for (int bb = 0; bb < 4; ++bb)
            xf[bb] = *(const bf16x8_t*)&As[cur][(wm + bb * 16 + m16) * 32 + g4 * 8];
#pragma unroll
        for (int a = 0; a < 4; ++a)
            wf[a] = *(const bf16x8_t*)&Bs[cur][(wn + a * 16 + m16) * 32 + g4 * 8];
#pragma unroll
        for (int a = 0; a < 4; ++a)
#pragma unroll
            for (int bb = 0; bb < 4; ++bb)
                acc[a][bb] = __builtin_amdgcn_mfma_f32_16x16x32_bf16(wf[a], xf[bb], acc[a][bb], 0, 0, 0);
    }

    unsigned short* pz = parts + (size_t)z * M * N;
#pragma unroll
    for (int a = 0; a < 4; ++a) {
        const int cb = n0 + wn + a * 16 + g4 * 4;
#pragma unroll
        for (int bb = 0; bb < 4; ++bb) {
            const int r = m0 + wm + bb * 16 + m16;
            const size_t idx = (size_t)r * N + cb;
            ushort4 o = {f2bf(acc[a][bb][0]), f2bf(acc[a][bb][1]),
                         f2bf(acc[a][bb][2]), f2bf(acc[a][bb][3])};
            *(ushort4*)(pz + idx) = o;
        }
    }
}

// ---------------------------------------------------------------------------
// fp8 split-K GEMM -> bf16 partials (acc/512).
// 1D grid 1024, XCD-swizzled m-tiles. z<2 -> (A1,W1) else (A2,W2).
// LDS reads are b128 (K-permuted pairs: both operands use the same g4*16
// mapping, so the dot product is unchanged).
// Act pre-scaled x16, weights x32 (+gamma folded) -> descale 1/512.
// ---------------------------------------------------------------------------
__global__ __launch_bounds__(256) void gemm_fp8_splitk_kernel(
        const unsigned char* __restrict__ A1,
        const unsigned char* __restrict__ W1,
        const unsigned char* __restrict__ A2,
        const unsigned char* __restrict__ W2,
        unsigned short* __restrict__ parts,
        int M, int N, int lda, int ldw, int Kc, int zsplit) {
    __shared__ unsigned char As[2][128 * 64];
    __shared__ unsigned char Bs[2][128 * 64];
    const int tid  = threadIdx.x;
    const int lane = tid & 63;
    const int wave = tid >> 6;
    const int m16  = lane & 15;
    const int g4   = lane >> 4;
    const int bid = blockIdx.x;
    const int xcd = bid & 7, l = bid >> 3;
    const int by = (xcd << 2) | (l & 3);   // m-tile (32)
    const int rr = l >> 2;
    const int bx = rr & 7;                 // n-tile (8)
    const int z  = rr >> 3;                // 0..3
    const int n0 = bx * 128;
    const int m0 = by * 128;
    const int wm = (wave >> 1) * 64;
    const int wn = (wave & 1) * 64;

    const unsigned char* A = (z < zsplit) ? A1 : A2;
    const unsigned char* W = (z < zsplit) ? W1 : W2;
    const int k0 = (z % zsplit) * Kc;

    const int r0  = tid >> 2;
    const int cc0 = (tid & 3) * 16;
    const unsigned char* agp0 = A + (size_t)(m0 + r0) * lda + k0 + cc0;
    const unsigned char* agp1 = A + (size_t)(m0 + r0 + 64) * lda + k0 + cc0;
    const unsigned char* bgp0 = W + (size_t)(n0 + r0) * ldw + k0 + cc0;
    const unsigned char* bgp1 = W + (size_t)(n0 + r0 + 64) * ldw + k0 + cc0;

    f32x4_t acc[4][4];
#pragma unroll
    for (int a = 0; a < 4; ++a)
#pragma unroll
        for (int bb = 0; bb < 4; ++bb) acc[a][bb] = zero4();

    auto stage = [&](int buf) {
        gload_lds16(agp0, &As[buf][wave * 1024]);
        gload_lds16(agp1, &As[buf][4096 + wave * 1024]);
        gload_lds16(bgp0, &Bs[buf][wave * 1024]);
        gload_lds16(bgp1, &Bs[buf][4096 + wave * 1024]);
        agp0 += 64; agp1 += 64; bgp0 += 64; bgp1 += 64;
    };

    stage(0);
    const int NIT = Kc >> 6;
    for (int it = 0; it < NIT; ++it) {
        const int cur = it & 1;
        __syncthreads();
        if (it + 1 < NIT) stage(cur ^ 1);
        l2_t xv[4], wv[4];
#pragma unroll
        for (int bb = 0; bb < 4; ++bb)
            xv[bb] = *(const l2_t*)&As[cur][(wm + bb * 16 + m16) * 64 + g4 * 16];
#pragma unroll
        for (int a = 0; a < 4; ++a)
            wv[a] = *(const l2_t*)&Bs[cur][(wn + a * 16 + m16) * 64 + g4 * 16];
#pragma unroll
        for (int a = 0; a < 4; ++a)
#pragma unroll
            for (int bb = 0; bb < 4; ++bb) {
                acc[a][bb] = __builtin_amdgcn_mfma_f32_16x16x32_fp8_fp8(wv[a][0], xv[bb][0], acc[a][bb], 0, 0, 0);
                acc[a][bb] = __builtin_amdgcn_mfma_f32_16x16x32_fp8_fp8(wv[a][1], xv[bb][1], acc[a][bb], 0, 0, 0);
            }
    }

    unsigned short* pz = parts + (size_t)z * M * N;
    const float ds = 1.0f / 512.0f;
#pragma unroll
    for (int a = 0; a < 4; ++a) {
        const int cb = n0 + wn + a * 16 + g4 * 4;
#pragma unroll
        for (int bb = 0; bb < 4; ++bb) {
            const int r = m0 + wm + bb * 16 + m16;
            const size_t idx = (size_t)r * N + cb;
            ushort4 o = {f2bf(acc[a][bb][0] * ds), f2bf(acc[a][bb][1] * ds),
                         f2bf(acc[a][bb][2] * ds), f2bf(acc[a][bb][3] * ds)};
            *(ushort4*)(pz + idx) = o;
        }
    }
}

// ---------------------------------------------------------------------------
// Split-K reduce: out[i] = resid[i] + bias[i%N] + sum_z parts[z][i]  (fp32 out)
// ---------------------------------------------------------------------------
template <int NP>
__global__ __launch_bounds__(256) void reduce_kernel(
        const unsigned short* __restrict__ parts,
        const float* __restrict__ resid,
        const float* __restrict__ bias,
        float* __restrict__ out, int MN, int N4mask) {
    int i = blockIdx.x * 256 + threadIdx.x;
    if (i * 4 >= MN) return;
    float4 res = ((const float4*)resid)[i];
    float4 bv  = *(const float4*)(bias + (i & N4mask) * 4);
    float4 o = {res.x + bv.x, res.y + bv.y, res.z + bv.z, res.w + bv.w};
#pragma unroll
    for (int z = 0; z < NP; ++z) {
        ushort4 u = ((const ushort4*)(parts + (size_t)z * MN))[i];
        o.x += bf2f(u.x); o.y += bf2f(u.y); o.z += bf2f(u.z); o.w += bf2f(u.w);
    }
    ((float4*)out)[i] = o;
}

// ---------------------------------------------------------------------------
// V^T pre-transpose with baked PV key-permutation.
// ---------------------------------------------------------------------------
__global__ __launch_bounds__(256) void vtrans_kernel(const unsigned short* __restrict__ qkv,
                                                     unsigned short* __restrict__ vt) {
    __shared__ unsigned short Vs[64 * 64];
    const int stile = blockIdx.x;
    const int bh = blockIdx.y;
    const int b = bh >> 4, h = bh & 15;
    const int tid = threadIdx.x;
#pragma unroll
    for (int j = 0; j < 2; ++j) {
        int c = j * 256 + tid;
        int r = c >> 3, d8 = (c & 7) * 8;
        int s = stile * 64 + r;
        uint4 v = {0u, 0u, 0u, 0u};
        if (s < Sv) v = *(const uint4*)(qkv + ((size_t)(b * Sv + s) * 3 + 2) * Cv + h * 64 + d8);
        *(uint4*)&Vs[r * 64 + d8] = v;
    }
    __syncthreads();
    const int d  = tid >> 2;
    const int p0 = (tid & 3) * 16;
    unsigned short tmp[16];
#pragma unroll
    for (int e = 0; e < 16; ++e) {
        int p = p0 + e;
        int s_local = (p & 32) + 16 * ((p >> 2) & 1) + 4 * ((p & 31) >> 3) + (p & 3);
        tmp[e] = Vs[s_local * 64 + d];
    }
    unsigned short* dst = vt + ((size_t)bh * 64 + d) * SPADv + stile * 64 + p0;
    *(uint4*)dst       = *(const uint4*)&tmp[0];
    *(uint4*)(dst + 8) = *(const uint4*)&tmp[8];
}

// ---------------------------------------------------------------------------
// Flash attention, S^T formulation.
// ---------------------------------------------------------------------------
__global__ __launch_bounds__(256) void attn_kernel(const unsigned short* __restrict__ qkv,
                                                   const unsigned short* __restrict__ vt,
                                                   unsigned short* __restrict__ o) {
    __shared__ unsigned short Qs[64 * 64];
    __shared__ unsigned short Ks[2][64 * 64];
    __shared__ unsigned short Vts[2][64 * 64];

    const int tid  = threadIdx.x;
    const int lane = tid & 63;
    const int wave = tid >> 6;
    const int m16  = lane & 15;
    const int g4   = lane >> 4;
    const int qt = blockIdx.x;
    const int bh = blockIdx.y;
    const int b = bh >> 4, h = bh & 15;

    const int lr = lane >> 3;
    const int csw = ((lane & 7) ^ lr) * 8;
    const int sw7 = m16 & 7;

#pragma unroll
    for (int j = 0; j < 2; ++j) {
        int r = wave * 16 + j * 8 + lr;
        int s = Iv + qt * 64 + r;
        gload_lds16(qkv + ((size_t)(b * Sv + s) * 3) * Cv + h * 64 + csw,
                    &Qs[(wave * 16 + j * 8) * 64]);
    }

    auto stage_kv = [&](int st, int buf) {
#pragma unroll
        for (int j = 0; j < 2; ++j) {
            int r = wave * 16 + j * 8 + lr;
            int s = st * 64 + r; if (s > Sv - 1) s = Sv - 1;
            gload_lds16(qkv + ((size_t)(b * Sv + s) * 3 + 1) * Cv + h * 64 + csw,
                        &Ks[buf][(wave * 16 + j * 8) * 64]);
            gload_lds16(vt + ((size_t)bh * 64 + r) * SPADv + st * 64 + csw,
                        &Vts[buf][(wave * 16 + j * 8) * 64]);
        }
    };

    f32x4_t oacc[4];
#pragma unroll
    for (int dt = 0; dt < 4; ++dt) oacc[dt] = zero4();
    float m_run = -1e30f, l_run = 0.f;

    stage_kv(0, 0);
    __syncthreads();

    const bf16x8_t qf0 = *(const bf16x8_t*)&Qs[(wave * 16 + m16) * 64 + ((g4 ^ sw7) * 8)];
    const bf16x8_t qf1 = *(const bf16x8_t*)&Qs[(wave * 16 + m16) * 64 + (((4 + g4) ^ sw7) * 8)];

    const int NT = (Sv + 63) / 64;   // 18
    for (int st = 0; st < NT; ++st) {
        const int cur = st & 1;
        if (st + 1 < NT) stage_kv(st + 1, cur ^ 1);

        f32x4_t sc[4];
#pragma unroll
        for (int kt = 0; kt < 4; ++kt) {
            bf16x8_t k0 = *(const bf16x8_t*)&Ks[cur][(kt * 16 + m16) * 64 + ((g4 ^ sw7) * 8)];
            bf16x8_t k1 = *(const bf16x8_t*)&Ks[cur][(kt * 16 + m16) * 64 + (((4 + g4) ^ sw7) * 8)];
            f32x4_t z = zero4();
            z = __builtin_amdgcn_mfma_f32_16x16x32_bf16(k0, qf0, z, 0, 0, 0);
            z = __builtin_amdgcn_mfma_f32_16x16x32_bf16(k1, qf1, z, 0, 0, 0);
            sc[kt] = z;
        }

        float mx = -1e30f;
#pragma unroll
        for (int kt = 0; kt < 4; ++kt)
#pragma unroll
            for (int r = 0; r < 4; ++r) {
                int key = st * 64 + kt * 16 + g4 * 4 + r;
                float v = sc[kt][r] * 0.125f;
                v = (key < Sv) ? v : -1e30f;
                sc[kt][r] = v;
                mx = fmaxf(mx, v);
            }
        mx = fmaxf(mx, __shfl_xor(mx, 16));
        mx = fmaxf(mx, __shfl_xor(mx, 32));
        const float mnew  = fmaxf(m_run, mx);
        const float alpha = __expf(m_run - mnew);
        m_run = mnew;
        float sum = 0.f;
#pragma unroll
        for (int kt = 0; kt < 4; ++kt)
#pragma unroll
            for (int r = 0; r < 4; ++r) {
                float p = __expf(sc[kt][r] - mnew);
                sc[kt][r] = p;
                sum += p;
            }
        sum += __shfl_xor(sum, 16);
        sum += __shfl_xor(sum, 32);
        l_run = l_run * alpha + sum;
#pragma unroll
        for (int dt = 0; dt < 4; ++dt) oacc[dt] *= alpha;

        us8_t pu0, pu1;
#pragma unroll
        for (int j = 0; j < 8; ++j) {
            pu0[j] = f2bf(sc[(j >> 2)][j & 3]);
            pu1[j] = f2bf(sc[2 + (j >> 2)][j & 3]);
        }
        const bf16x8_t pf0 = __builtin_bit_cast(bf16x8_t, pu0);
        const bf16x8_t pf1 = __builtin_bit_cast(bf16x8_t, pu1);

#pragma unroll
        for (int dt = 0; dt < 4; ++dt) {
            bf16x8_t v0 = *(const bf16x8_t*)&Vts[cur][(dt * 16 + m16) * 64 + ((g4 ^ sw7) * 8)];
            bf16x8_t v1 = *(const bf16x8_t*)&Vts[cur][(dt * 16 + m16) * 64 + (((4 + g4) ^ sw7) * 8)];
            oacc[dt] = __builtin_amdgcn_mfma_f32_16x16x32_bf16(v0, pf0, oacc[dt], 0, 0, 0);
            oacc[dt] = __builtin_amdgcn_mfma_f32_16x16x32_bf16(v1, pf1, oacc[dt], 0, 0, 0);
        }
        __syncthreads();
    }

    const float inv = 1.0f / l_run;
    const int q = qt * 64 + wave * 16 + m16;
    const size_t row = (size_t)(b * Nv + q) * Cv + h * 64;
#pragma unroll
    for (int dt = 0; dt < 4; ++dt) {
        ushort4 o4 = {f2bf(oacc[dt][0] * inv), f2bf(oacc[dt][1] * inv),
                      f2bf(oacc[dt][2] * inv), f2bf(oacc[dt][3] * inv)};
        *(ushort4*)&o[row + dt * 16 + g4 * 4] = o4;
    }
}

// ---------------------------------------------------------------------------
// Launcher
// ---------------------------------------------------------------------------
extern "C" void kernel_launch(void* const* d_in, const int* in_sizes, int n_in,
                              void* d_out, int out_size, void* d_ws, size_t ws_size,
                              hipStream_t stream) {
    (void)in_sizes; (void)n_in; (void)out_size; (void)ws_size;
    const float* x       = (const float*)d_in[0];
    const float* instr   = (const float*)d_in[1];
    const float* norm1_w = (const float*)d_in[2];
    const float* norm1_b = (const float*)d_in[3];
    const float* qkv_w   = (const float*)d_in[4];
    const float* q_bias  = (const float*)d_in[5];
    const float* v_bias  = (const float*)d_in[6];
    const float* proj_w  = (const float*)d_in[7];
    const float* proj_b  = (const float*)d_in[8];
    const float* gamma_1 = (const float*)d_in[9];
    const float* gamma_2 = (const float*)d_in[10];
    const float* norm2_w = (const float*)d_in[11];
    const float* norm2_b = (const float*)d_in[12];
    const float* fc1_w   = (const float*)d_in[13];
    const float* fc1_b   = (const float*)d_in[14];
    const float* fc2_w   = (const float*)d_in[15];
    const float* fc2_b   = (const float*)d_in[16];
    const float* pfc1_w  = (const float*)d_in[17];
    const float* pfc1_b  = (const float*)d_in[18];
    const float* pfc2_w  = (const float*)d_in[19];
    const float* pfc2_b  = (const float*)d_in[20];
    const float* gate    = (const float*)d_in[21];
    const float* ir_ln_w = (const float*)d_in[22];
    const float* ir_ln_b = (const float*)d_in[23];
    const float* ir_l1_w = (const float*)d_in[24];
    const float* ir_l1_b = (const float*)d_in[25];
    const float* ir_l2_w = (const float*)d_in[26];
    const float* ir_l2_b = (const float*)d_in[27];
    float* out = (float*)d_out;

    char* ws = (char*)d_ws;
    size_t off = 0;
    auto alloc = [&](size_t bytes) -> char* {
        char* p = ws + off;
        off += (bytes + 255) & ~(size_t)255;
        return p;
    };
    unsigned short* w_qkv  = (unsigned short*)alloc((size_t)3 * Cv * Cv * 2);
    unsigned short* w_proj = (unsigned short*)alloc((size_t)Cv * Cv * 2);      // *g1
    unsigned short* w_fc1  = (unsigned short*)alloc((size_t)HIDv * Cv * 2);    // bf16
    unsigned char*  w_fc2  = (unsigned char*)alloc((size_t)Cv * HIDv);         // fp8 *g2*32
    unsigned short* w_pfc1 = (unsigned short*)alloc((size_t)HIDv * Cv * 2);    // bf16
    unsigned char*  w_pfc2 = (unsigned char*)alloc((size_t)Cv * HIDv);         // fp8 *gate*32
    unsigned short* w_ir1  = (unsigned short*)alloc((size_t)Cv * IDv * 2);
    unsigned short* w_ir2  = (unsigned short*)alloc((size_t)Cv * Cv * 2);
    float*          qkvb   = (float*)alloc((size_t)3 * Cv * 4);
    float*          bfuse  = (float*)alloc((size_t)Cv * 4);
    float*          projb  = (float*)alloc((size_t)Cv * 4);
    unsigned short* irln   = (unsigned short*)alloc((size_t)BIv * IDv * 2);
    unsigned short* h1     = (unsigned short*)alloc((size_t)BIv * Cv * 2);
    unsigned short* kvtmp  = (unsigned short*)alloc((size_t)BIv * Cv * 2);
    unsigned short* cat    = (unsigned short*)alloc((size_t)BSv * Cv * 2);      // 9.0 MB
    unsigned short* qkvbuf = (unsigned short*)alloc((size_t)BSv * 3 * Cv * 2);  // 27.1 MB
    unsigned short* obuf   = (unsigned short*)alloc((size_t)BNv * Cv * 2);
    float*          x1     = (float*)alloc((size_t)BNv * Cv * 4);
    unsigned short* ybuf   = (unsigned short*)alloc((size_t)BNv * Cv * 2);
    unsigned char*  gbufA  = (unsigned char*)alloc((size_t)BNv * 2 * HIDv);     // fp8 33.6 MB
    unsigned short* fpart  = (unsigned short*)alloc((size_t)4 * BNv * Cv * 2);  // 33.6 MB
    unsigned short* vt     = (unsigned short*)gbufA;  // vt dead before fc1 writes gbufA
    unsigned short* ppart  = cat;                     // cat+qkvbuf dead after attn

    cvt8_kernel<<<22272, 256, 0, stream>>>(qkv_w, proj_w, fc1_w, fc2_w, pfc1_w, pfc2_w,
                                           ir_l1_w, ir_l2_w,
                                           w_qkv, w_proj, w_fc1, w_fc2, w_pfc1, w_pfc2,
                                           w_ir1, w_ir2,
                                           gamma_1, gamma_2, gate);

    bias_prep_kernel<<<20, 256, 0, stream>>>(q_bias, v_bias, fc2_b, pfc2_b, proj_b,
                                             gamma_1, gamma_2, gate,
                                             qkvb, bfuse, projb);

    // instruct branch: LN -> Linear+GELU -> Linear
    ln_kernel<<<BIv, 256, 0, stream>>>(instr, ir_ln_w, ir_ln_b, irln,
                                       IDv, 1.0f / IDv, 1 << 28, 0, 0);
    // LN1 writes directly into cat rows b*S + I + n
    ln_kernel<<<BNv, 256, 0, stream>>>(x, norm1_w, norm1_b, cat,
                                       Cv, 1.0f / Cv, Nv, Sv, Iv);
    gemm_bf16_kernel<1, 0><<<dim3(Cv / 128, (BIv + 127) / 128), 256, 0, stream>>>(
        irln, w_ir1, ir_l1_b, h1, BIv, Cv, IDv, Cv, 0);
    gemm_bf16_kernel<0, 0><<<dim3(Cv / 128, (BIv + 127) / 128), 256, 0, stream>>>(
        h1, w_ir2, ir_l2_b, kvtmp, BIv, Cv, Cv, Cv, 0);
    scatter_kv_kernel<<<BIv, 256, 0, stream>>>(kvtmp, cat);

    // QKV projection over cat [BS, C] -> [BS, 3C]
    gemm_bf16_kernel<0, 0><<<dim3(3 * Cv / 128, (BSv + 127) / 128), 256, 0, stream>>>(
        cat, w_qkv, qkvb, qkvbuf, BSv, 3 * Cv, Cv, 3 * Cv, 0);

    // V^T pre-transpose (permuted), then attention
    vtrans_kernel<<<dim3(18, Bv * Hv), 256, 0, stream>>>(qkvbuf, vt);
    attn_kernel<<<dim3(Nv / 64, Bv * Hv), 256, 0, stream>>>(qkvbuf, vt, obuf);

    // proj split-K=4 (bf16 partials, XCD-swizzled), reduce into x1
    gemm_splitk_kernel<<<1024, 256, 0, stream>>>(
        obuf, w_proj, ppart, BNv, Cv, Cv, Cv / 4);
    reduce_kernel<4><<<(BNv * Cv / 4 + 255) / 256, 256, 0, stream>>>(
        ppart, x, projb, x1, BNv * Cv, Cv / 4 - 1);

    // LN2 (bf16)
    ln_kernel<<<BNv, 256, 0, stream>>>(x1, norm2_w, norm2_b, ybuf,
                                       Cv, 1.0f / Cv, 1 << 28, 0, 0);

    // fc1 / pfc1: bf16 mainloop, fp8(16*gelu) epilogue into gbufA halves
    gemm_bf16_kernel<2, 1><<<1024, 256, 0, stream>>>(
        ybuf, w_fc1, fc1_b, gbufA, BNv, HIDv, Cv, 2 * HIDv, 0);
    gemm_bf16_kernel<2, 1><<<1024, 256, 0, stream>>>(
        ybuf, w_pfc1, pfc1_b, gbufA, BNv, HIDv, Cv, 2 * HIDv, HIDv);

    // fc2 + pfc2 fp8 split-K (XCD-swizzled; z=0,1 -> fc2 halves; z=2,3 -> pfc2)
    gemm_fp8_splitk_kernel<<<1024, 256, 0, stream>>>(
        gbufA, w_fc2, gbufA + HIDv, w_pfc2, fpart,
        BNv, Cv, 2 * HIDv, HIDv, HIDv / 2, 2);
    // out = x1 + (g2*fc2_b + gate*pfc2_b) + sum(parts)
    reduce_kernel<4><<<(BNv * Cv / 4 + 255) / 256, 256, 0, stream>>>(
        fpart, x1, bfuse, out, BNv * Cv, Cv / 4 - 1);
}

// Round 8
// 505.234 us; speedup vs baseline: 1.2901x; 1.1255x over previous
//
#include <hip/hip_runtime.h>
#include <cstdint>

// ---------------------------------------------------------------------------
// Problem constants
// ---------------------------------------------------------------------------
#define Bv   4
#define Nv   1024
#define Cv   1024
#define Hv   16
#define Iv   77
#define IDv  768
#define HDv  64
#define HIDv 4096
#define Sv   (Iv + Nv)      // 1101
#define BIv  (Bv * Iv)      // 308
#define BSv  (Bv * Sv)      // 4404
#define BNv  (Bv * Nv)      // 4096
#define SPADv 1152          // 18*64, zero-padded key dim for V^T

typedef __bf16 bf16x8_t __attribute__((ext_vector_type(8)));
typedef float  f32x4_t  __attribute__((ext_vector_type(4)));
typedef unsigned short us8_t __attribute__((ext_vector_type(8)));
typedef long  l2_t  __attribute__((ext_vector_type(2)));

__device__ inline f32x4_t zero4() { f32x4_t z; z[0]=0.f; z[1]=0.f; z[2]=0.f; z[3]=0.f; return z; }

// float -> bf16, round-nearest-even
__device__ inline unsigned short f2bf(float f) {
    unsigned int u = __builtin_bit_cast(unsigned int, f);
    u = (u + 0x7fffu + ((u >> 16) & 1u)) >> 16;
    return (unsigned short)u;
}
__device__ inline float bf2f(unsigned short u) {
    return __builtin_bit_cast(float, ((unsigned int)u) << 16);
}
// 4 floats -> packed fp8 e4m3 (HW convert, RNE sat)
__device__ inline unsigned int f4_fp8(float a, float b, float c, float d) {
    int v = __builtin_amdgcn_cvt_pk_fp8_f32(a, b, 0, false);
    v = __builtin_amdgcn_cvt_pk_fp8_f32(c, d, v, true);
    return (unsigned int)v;
}

// fast GELU (tanh approx via HW exp; max abs err ~1e-3, gamma-damped downstream)
__device__ inline float gelu_f(float x) {
    float u = 0.7978845608f * x * (1.0f + 0.044715f * x * x);
    float e = __expf(2.0f * u);
    float t = 1.0f - 2.0f / (e + 1.0f);
    return 0.5f * x * (1.0f + t);
}

// async global(16B/lane) -> LDS  (dest = wave-uniform base + lane*16)
__device__ inline void gload_lds16(const void* g, void* l) {
    __builtin_amdgcn_global_load_lds(
        (__attribute__((address_space(1))) void*)(unsigned long long)g,
        (__attribute__((address_space(3))) void*)(unsigned long long)l,
        16, 0, 0);
}

// ---------------------------------------------------------------------------
// Fused weight convert. bf16 for qkv/proj/ir; fp8 x32 (gamma-folded) for MLP.
// order: qkv | proj(*g1) | fc1 | fc2(*g2) | pfc1 | pfc2(*gate) | ir1 | ir2
// ---------------------------------------------------------------------------
__global__ __launch_bounds__(256) void cvt8_kernel(
        const float* s0, const float* s1, const float* s2, const float* s3,
        const float* s4, const float* s5, const float* s6, const float* s7,
        void* d0, void* d1, void* d2, void* d3,
        void* d4, void* d5, void* d6, void* d7,
        const float* g1, const float* g2, const float* gate) {
    long i = (long)blockIdx.x * 256 + threadIdx.x;
    const float* src; void* dst; long off;
    const float* sptr = nullptr; int K4 = 1; float wmul = 1.0f; bool f8 = false;
    if (i < 2097152) {
        if (i < 786432)       { src = s0; dst = d0; off = i; }
        else if (i < 1048576) { src = s1; dst = d1; off = i - 786432;  sptr = g1; K4 = 256; }
        else                  { src = s2; dst = d2; off = i - 1048576; f8 = true; wmul = 32.f; }
    } else if (i < 4194304) {
        if (i < 3145728)      { src = s3; dst = d3; off = i - 2097152; f8 = true; wmul = 32.f; sptr = g2; K4 = 1024; }
        else                  { src = s4; dst = d4; off = i - 3145728; f8 = true; wmul = 32.f; }
    } else {
        if (i < 5242880)      { src = s5; dst = d5; off = i - 4194304; f8 = true; wmul = 32.f; sptr = gate; K4 = 0x7fffffff; }
        else if (i < 5439488) { src = s6; dst = d6; off = i - 5242880; }
        else                  { src = s7; dst = d7; off = i - 5439488; }
    }
    float sc = (sptr ? sptr[(int)(off / K4)] : 1.0f) * wmul;
    float4 v = ((const float4*)src)[off];
    if (f8) {
        ((unsigned int*)dst)[off] = f4_fp8(v.x * sc, v.y * sc, v.z * sc, v.w * sc);
    } else {
        ushort4 o = {f2bf(v.x * sc), f2bf(v.y * sc), f2bf(v.z * sc), f2bf(v.w * sc)};
        ((ushort4*)dst)[off] = o;
    }
}

// qkvb=[qb,0,vb]; bfuse=g2*fc2b+gate*pfc2b; projb=g1*projb; bcat=[fc1b,pfc1b]
__global__ __launch_bounds__(256) void bias_prep_kernel(
        const float* __restrict__ qb, const float* __restrict__ vb,
        const float* __restrict__ fc2b, const float* __restrict__ pfc2b,
        const float* __restrict__ projb_in,
        const float* __restrict__ fc1b, const float* __restrict__ pfc1b,
        const float* __restrict__ g1, const float* __restrict__ g2,
        const float* __restrict__ gate,
        float* __restrict__ qkvb, float* __restrict__ bfuse,
        float* __restrict__ projb, float* __restrict__ bcat) {
    int i = blockIdx.x * 256 + threadIdx.x;
    if (i < 3 * Cv) {
        float v = 0.f;
        if (i < Cv) v = qb[i];
        else if (i >= 2 * Cv) v = vb[i - 2 * Cv];
        qkvb[i] = v;
    } else if (i < 4 * Cv) {
        int n = i - 3 * Cv;
        bfuse[n] = g2[n] * fc2b[n] + gate[0] * pfc2b[n];
    } else if (i < 5 * Cv) {
        int n = i - 4 * Cv;
        projb[n] = g1[n] * projb_in[n];
    } else if (i < 13 * Cv) {
        int j = i - 5 * Cv;
        bcat[j] = (j < HIDv) ? fc1b[j] : pfc1b[j - HIDv];
    }
}

// scatter kv rows [BI, C] bf16 into cat rows b*S + i
__global__ __launch_bounds__(256) void scatter_kv_kernel(const unsigned short* __restrict__ kv,
                                                         unsigned short* __restrict__ cat) {
    int r = blockIdx.x;
    int b = r / Iv, i = r % Iv;
    const uint2* src = (const uint2*)(kv + (size_t)r * Cv);
    uint2* dst = (uint2*)(cat + (size_t)(b * Sv + i) * Cv);
    dst[threadIdx.x] = src[threadIdx.x];
}

// ---------------------------------------------------------------------------
// LayerNorm (fp32 in) -> bf16 (F8=0) or fp8(16*y) (F8=1), one row per block.
// out row index = (r/div)*stride + r%div + off
// ---------------------------------------------------------------------------
template <int F8>
__global__ __launch_bounds__(256) void ln_kernel(const float* __restrict__ in,
                                                 const float* __restrict__ w,
                                                 const float* __restrict__ bvec,
                                                 void* __restrict__ out,
                                                 int cols, float invcols,
                                                 int div_, int stride_, int off_) {
    const int r = blockIdx.x;
    const int tid = threadIdx.x;
    const float* row = in + (size_t)r * cols;
    float s = 0.f, s2 = 0.f;
    for (int c = tid * 4; c < cols; c += 1024) {
        float4 v = *(const float4*)(row + c);
        s  += v.x + v.y + v.z + v.w;
        s2 += v.x * v.x + v.y * v.y + v.z * v.z + v.w * v.w;
    }
#pragma unroll
    for (int o2 = 32; o2 > 0; o2 >>= 1) { s += __shfl_down(s, o2); s2 += __shfl_down(s2, o2); }
    __shared__ float sh[10];
    const int lane = tid & 63, wave = tid >> 6;
    if (lane == 0) { sh[wave] = s; sh[4 + wave] = s2; }
    __syncthreads();
    if (tid == 0) {
        float S1 = sh[0] + sh[1] + sh[2] + sh[3];
        float S2 = sh[4] + sh[5] + sh[6] + sh[7];
        float mean = S1 * invcols;
        float var  = S2 * invcols - mean * mean;
        sh[8] = mean;
        sh[9] = rsqrtf(var + 1e-5f);
    }
    __syncthreads();
    const float mean = sh[8], rstd = sh[9];
    const size_t orow = (size_t)((r / div_) * stride_ + (r % div_) + off_) * cols;
    for (int c = tid * 4; c < cols; c += 1024) {
        float4 v  = *(const float4*)(row + c);
        float4 wv = *(const float4*)(w + c);
        float4 bv = *(const float4*)(bvec + c);
        float o0 = (v.x - mean) * rstd * wv.x + bv.x;
        float o1 = (v.y - mean) * rstd * wv.y + bv.y;
        float o2 = (v.z - mean) * rstd * wv.z + bv.z;
        float o3 = (v.w - mean) * rstd * wv.w + bv.w;
        if constexpr (F8) {
            *(unsigned int*)((unsigned char*)out + orow + c) =
                f4_fp8(o0 * 16.f, o1 * 16.f, o2 * 16.f, o3 * 16.f);
        } else {
            ushort4 o = {f2bf(o0), f2bf(o1), f2bf(o2), f2bf(o3)};
            *(ushort4*)((unsigned short*)out + orow + c) = o;
        }
    }
}

// ---------------------------------------------------------------------------
// bf16 GEMM (128x128, BK=32, dbuf LDS). MODE 0: bf16 out; MODE 1: gelu bf16.
// ---------------------------------------------------------------------------
template <int MODE>
__global__ __launch_bounds__(256) void gemm_bf16_kernel(
        const unsigned short* __restrict__ A,
        const unsigned short* __restrict__ W,
        const float* __restrict__ bias,
        unsigned short* __restrict__ outp,
        int M, int N, int K) {
    __shared__ unsigned short As[2][128 * 32];
    __shared__ unsigned short Bs[2][128 * 32];
    const int tid  = threadIdx.x;
    const int lane = tid & 63;
    const int wave = tid >> 6;
    const int m16  = lane & 15;
    const int g4   = lane >> 4;
    const int n0 = blockIdx.x * 128;
    const int m0 = blockIdx.y * 128;
    const int wm = (wave >> 1) * 64;
    const int wn = (wave & 1) * 64;

    const int r0  = tid >> 2;
    const int cc0 = (tid & 3) * 8;
    int am0 = m0 + r0;       if (am0 > M - 1) am0 = M - 1;
    int am1 = m0 + r0 + 64;  if (am1 > M - 1) am1 = M - 1;
    const unsigned short* agp0 = A + (size_t)am0 * K + cc0;
    const unsigned short* agp1 = A + (size_t)am1 * K + cc0;
    const unsigned short* bgp0 = W + (size_t)(n0 + r0) * K + cc0;
    const unsigned short* bgp1 = W + (size_t)(n0 + r0 + 64) * K + cc0;

    f32x4_t acc[4][4];
#pragma unroll
    for (int a = 0; a < 4; ++a)
#pragma unroll
        for (int bb = 0; bb < 4; ++bb) acc[a][bb] = zero4();

    auto stage = [&](int buf) {
        gload_lds16(agp0, &As[buf][wave * 512]);
        gload_lds16(agp1, &As[buf][2048 + wave * 512]);
        gload_lds16(bgp0, &Bs[buf][wave * 512]);
        gload_lds16(bgp1, &Bs[buf][2048 + wave * 512]);
        agp0 += 32; agp1 += 32; bgp0 += 32; bgp1 += 32;
    };

    stage(0);
    const int NIT = K >> 5;
    for (int it = 0; it < NIT; ++it) {
        const int cur = it & 1;
        __syncthreads();
        if (it + 1 < NIT) stage(cur ^ 1);
        bf16x8_t xf[4], wf[4];
#pragma unroll
        for (int bb = 0; bb < 4; ++bb)
            xf[bb] = *(const bf16x8_t*)&As[cur][(wm + bb * 16 + m16) * 32 + g4 * 8];
#pragma unroll
        for (int a = 0; a < 4; ++a)
            wf[a] = *(const bf16x8_t*)&Bs[cur][(wn + a * 16 + m16) * 32 + g4 * 8];
#pragma unroll
        for (int a = 0; a < 4; ++a)
#pragma unroll
            for (int bb = 0; bb < 4; ++bb)
                acc[a][bb] = __builtin_amdgcn_mfma_f32_16x16x32_bf16(wf[a], xf[bb], acc[a][bb], 0, 0, 0);
    }

#pragma unroll
    for (int a = 0; a < 4; ++a) {
        const int cb = n0 + wn + a * 16 + g4 * 4;
        const float4 bv4 = *(const float4*)(bias + cb);
#pragma unroll
        for (int bb = 0; bb < 4; ++bb) {
            const int r = m0 + wm + bb * 16 + m16;
            if (r < M) {
                const size_t idx = (size_t)r * N + cb;
                const float v0 = acc[a][bb][0] + bv4.x;
                const float v1 = acc[a][bb][1] + bv4.y;
                const float v2 = acc[a][bb][2] + bv4.z;
                const float v3 = acc[a][bb][3] + bv4.w;
                if constexpr (MODE == 0) {
                    ushort4 o = {f2bf(v0), f2bf(v1), f2bf(v2), f2bf(v3)};
                    *(ushort4*)(outp + idx) = o;
                } else {
                    ushort4 o = {f2bf(gelu_f(v0)), f2bf(gelu_f(v1)),
                                 f2bf(gelu_f(v2)), f2bf(gelu_f(v3))};
                    *(ushort4*)(outp + idx) = o;
                }
            }
        }
    }
}

// ---------------------------------------------------------------------------
// bf16 split-K GEMM -> private bf16 partials (proj).
// 1D grid 1024, XCD-swizzled m-tiles. N=1024(8 nt), z=4.
// ---------------------------------------------------------------------------
__global__ __launch_bounds__(256) void gemm_splitk_kernel(
        const unsigned short* __restrict__ A1,
        const unsigned short* __restrict__ W1,
        unsigned short* __restrict__ parts,
        int M, int N, int KA, int Kc) {
    __shared__ unsigned short As[2][128 * 32];
    __shared__ unsigned short Bs[2][128 * 32];
    const int tid  = threadIdx.x;
    const int lane = tid & 63;
    const int wave = tid >> 6;
    const int m16  = lane & 15;
    const int g4   = lane >> 4;
    const int bid = blockIdx.x;
    const int xcd = bid & 7, l = bid >> 3;
    const int by = (xcd << 2) | (l & 3);
    const int rr = l >> 2;
    const int bx = rr & 7;
    const int z  = rr >> 3;
    const int n0 = bx * 128;
    const int m0 = by * 128;
    const int wm = (wave >> 1) * 64;
    const int wn = (wave & 1) * 64;
    const int k0 = z * Kc;

    const int r0  = tid >> 2;
    const int cc0 = (tid & 3) * 8;
    const unsigned short* agp0 = A1 + (size_t)(m0 + r0) * KA + k0 + cc0;
    const unsigned short* agp1 = A1 + (size_t)(m0 + r0 + 64) * KA + k0 + cc0;
    const unsigned short* bgp0 = W1 + (size_t)(n0 + r0) * KA + k0 + cc0;
    const unsigned short* bgp1 = W1 + (size_t)(n0 + r0 + 64) * KA + k0 + cc0;

    f32x4_t acc[4][4];
#pragma unroll
    for (int a = 0; a < 4; ++a)
#pragma unroll
        for (int bb = 0; bb < 4; ++bb) acc[a][bb] = zero4();

    auto stage = [&](int buf) {
        gload_lds16(agp0, &As[buf][wave * 512]);
        gload_lds16(agp1, &As[buf][2048 + wave * 512]);
        gload_lds16(bgp0, &Bs[buf][wave * 512]);
        gload_lds16(bgp1, &Bs[buf][2048 + wave * 512]);
        agp0 += 32; agp1 += 32; bgp0 += 32; bgp1 += 32;
    };

    stage(0);
    const int NIT = Kc >> 5;
    for (int it = 0; it < NIT; ++it) {
        const int cur = it & 1;
        __syncthreads();
        if (it + 1 < NIT) stage(cur ^ 1);
        bf16x8_t xf[4], wf[4];
#pragma unroll
        for (int bb = 0; bb < 4; ++bb)
            xf[bb] = *(const bf16x8_t*)&As[cur][(wm + bb * 16 + m16) * 32 + g4 * 8];
#pragma unroll
        for (int a = 0; a < 4; ++a)
            wf[a] = *(const bf16x8_t*)&Bs[cur][(wn + a * 16 + m16) * 32 + g4 * 8];
#pragma unroll
        for (int a = 0; a < 4; ++a)
#pragma unroll
            for (int bb = 0; bb < 4; ++bb)
                acc[a][bb] = __builtin_amdgcn_mfma_f32_16x16x32_bf16(wf[a], xf[bb], acc[a][bb], 0, 0, 0);
    }

    unsigned short* pz = parts + (size_t)z * M * N;
#pragma unroll
    for (int a = 0; a < 4; ++a) {
        const int cb = n0 + wn + a * 16 + g4 * 4;
#pragma unroll
        for (int bb = 0; bb < 4; ++bb) {
            const int r = m0 + wm + bb * 16 + m16;
            const size_t idx = (size_t)r * N + cb;
            ushort4 o = {f2bf(acc[a][bb][0]), f2bf(acc[a][bb][1]),
                         f2bf(acc[a][bb][2]), f2bf(acc[a][bb][3])};
            *(ushort4*)(pz + idx) = o;
        }
    }
}

// ---------------------------------------------------------------------------
// fp8 GEMM, BK=64, b128 K-permuted LDS reads, XCD-swizzled 1D grid (2048).
// Fused fc1+pfc1: A [M,K] fp8 (x16), W [N,K] fp8 (x32), N = 8192.
// out fp8 = fp8( 16 * gelu(acc/512 + bias) ).
// ---------------------------------------------------------------------------
__global__ __launch_bounds__(256) void gemm_fp8_gelu_kernel(
        const unsigned char* __restrict__ A,
        const unsigned char* __restrict__ W,
        const float* __restrict__ bias,
        unsigned char* __restrict__ outp,
        int M, int N, int K) {
    __shared__ unsigned char As[2][128 * 64];
    __shared__ unsigned char Bs[2][128 * 64];
    const int tid  = threadIdx.x;
    const int lane = tid & 63;
    const int wave = tid >> 6;
    const int m16  = lane & 15;
    const int g4   = lane >> 4;
    const int bid = blockIdx.x;
    const int xcd = bid & 7, l = bid >> 3;
    const int by = (xcd << 2) | (l & 3);   // m-tile (32)
    const int bx = l >> 2;                 // n-tile (64)
    const int n0 = bx * 128;
    const int m0 = by * 128;
    const int wm = (wave >> 1) * 64;
    const int wn = (wave & 1) * 64;

    const int r0  = tid >> 2;
    const int cc0 = (tid & 3) * 16;
    const unsigned char* agp0 = A + (size_t)(m0 + r0) * K + cc0;
    const unsigned char* agp1 = A + (size_t)(m0 + r0 + 64) * K + cc0;
    const unsigned char* bgp0 = W + (size_t)(n0 + r0) * K + cc0;
    const unsigned char* bgp1 = W + (size_t)(n0 + r0 + 64) * K + cc0;

    f32x4_t acc[4][4];
#pragma unroll
    for (int a = 0; a < 4; ++a)
#pragma unroll
        for (int bb = 0; bb < 4; ++bb) acc[a][bb] = zero4();

    auto stage = [&](int buf) {
        gload_lds16(agp0, &As[buf][wave * 1024]);
        gload_lds16(agp1, &As[buf][4096 + wave * 1024]);
        gload_lds16(bgp0, &Bs[buf][wave * 1024]);
        gload_lds16(bgp1, &Bs[buf][4096 + wave * 1024]);
        agp0 += 64; agp1 += 64; bgp0 += 64; bgp1 += 64;
    };

    stage(0);
    const int NIT = K >> 6;
    for (int it = 0; it < NIT; ++it) {
        const int cur = it & 1;
        __syncthreads();
        if (it + 1 < NIT) stage(cur ^ 1);
        l2_t xv[4], wv[4];
#pragma unroll
        for (int bb = 0; bb < 4; ++bb)
            xv[bb] = *(const l2_t*)&As[cur][(wm + bb * 16 + m16) * 64 + g4 * 16];
#pragma unroll
        for (int a = 0; a < 4; ++a)
            wv[a] = *(const l2_t*)&Bs[cur][(wn + a * 16 + m16) * 64 + g4 * 16];
#pragma unroll
        for (int a = 0; a < 4; ++a)
#pragma unroll
            for (int bb = 0; bb < 4; ++bb) {
                acc[a][bb] = __builtin_amdgcn_mfma_f32_16x16x32_fp8_fp8(wv[a][0], xv[bb][0], acc[a][bb], 0, 0, 0);
                acc[a][bb] = __builtin_amdgcn_mfma_f32_16x16x32_fp8_fp8(wv[a][1], xv[bb][1], acc[a][bb], 0, 0, 0);
            }
    }

    const float ds = 1.0f / 512.0f;
#pragma unroll
    for (int a = 0; a < 4; ++a) {
        const int cb = n0 + wn + a * 16 + g4 * 4;
        const float4 bv4 = *(const float4*)(bias + cb);
#pragma unroll
        for (int bb = 0; bb < 4; ++bb) {
            const int r = m0 + wm + bb * 16 + m16;
            const size_t idx = (size_t)r * N + cb;
            unsigned int pk = f4_fp8(gelu_f(acc[a][bb][0] * ds + bv4.x) * 16.f,
                                     gelu_f(acc[a][bb][1] * ds + bv4.y) * 16.f,
                                     gelu_f(acc[a][bb][2] * ds + bv4.z) * 16.f,
                                     gelu_f(acc[a][bb][3] * ds + bv4.w) * 16.f);
            *(unsigned int*)(outp + idx) = pk;
        }
    }
}

// ---------------------------------------------------------------------------
// fp8 split-K GEMM -> bf16 partials (acc/512). XCD-swizzled 1D grid (1024).
// z<zsplit -> (A1,W1) else (A2,W2). b128 K-permuted LDS reads.
// ---------------------------------------------------------------------------
__global__ __launch_bounds__(256) void gemm_fp8_splitk_kernel(
        const unsigned char* __restrict__ A1,
        const unsigned char* __restrict__ W1,
        const unsigned char* __restrict__ A2,
        const unsigned char* __restrict__ W2,
        unsigned short* __restrict__ parts,
        int M, int N, int lda, int ldw, int Kc, int zsplit) {
    __shared__ unsigned char As[2][128 * 64];
    __shared__ unsigned char Bs[2][128 * 64];
    const int tid  = threadIdx.x;
    const int lane = tid & 63;
    const int wave = tid >> 6;
    const int m16  = lane & 15;
    const int g4   = lane >> 4;
    const int bid = blockIdx.x;
    const int xcd = bid & 7, l = bid >> 3;
    const int by = (xcd << 2) | (l & 3);
    const int rr = l >> 2;
    const int bx = rr & 7;
    const int z  = rr >> 3;
    const int n0 = bx * 128;
    const int m0 = by * 128;
    const int wm = (wave >> 1) * 64;
    const int wn = (wave & 1) * 64;

    const unsigned char* A = (z < zsplit) ? A1 : A2;
    const unsigned char* W = (z < zsplit) ? W1 : W2;
    const int k0 = (z % zsplit) * Kc;

    const int r0  = tid >> 2;
    const int cc0 = (tid & 3) * 16;
    const unsigned char* agp0 = A + (size_t)(m0 + r0) * lda + k0 + cc0;
    const unsigned char* agp1 = A + (size_t)(m0 + r0 + 64) * lda + k0 + cc0;
    const unsigned char* bgp0 = W + (size_t)(n0 + r0) * ldw + k0 + cc0;
    const unsigned char* bgp1 = W + (size_t)(n0 + r0 + 64) * ldw + k0 + cc0;

    f32x4_t acc[4][4];
#pragma unroll
    for (int a = 0; a < 4; ++a)
#pragma unroll
        for (int bb = 0; bb < 4; ++bb) acc[a][bb] = zero4();

    auto stage = [&](int buf) {
        gload_lds16(agp0, &As[buf][wave * 1024]);
        gload_lds16(agp1, &As[buf][4096 + wave * 1024]);
        gload_lds16(bgp0, &Bs[buf][wave * 1024]);
        gload_lds16(bgp1, &Bs[buf][4096 + wave * 1024]);
        agp0 += 64; agp1 += 64; bgp0 += 64; bgp1 += 64;
    };

    stage(0);
    const int NIT = Kc >> 6;
    for (int it = 0; it < NIT; ++it) {
        const int cur = it & 1;
        __syncthreads();
        if (it + 1 < NIT) stage(cur ^ 1);
        l2_t xv[4], wv[4];
#pragma unroll
        for (int bb = 0; bb < 4; ++bb)
            xv[bb] = *(const l2_t*)&As[cur][(wm + bb * 16 + m16) * 64 + g4 * 16];
#pragma unroll
        for (int a = 0; a < 4; ++a)
            wv[a] = *(const l2_t*)&Bs[cur][(wn + a * 16 + m16) * 64 + g4 * 16];
#pragma unroll
        for (int a = 0; a < 4; ++a)
#pragma unroll
            for (int bb = 0; bb < 4; ++bb) {
                acc[a][bb] = __builtin_amdgcn_mfma_f32_16x16x32_fp8_fp8(wv[a][0], xv[bb][0], acc[a][bb], 0, 0, 0);
                acc[a][bb] = __builtin_amdgcn_mfma_f32_16x16x32_fp8_fp8(wv[a][1], xv[bb][1], acc[a][bb], 0, 0, 0);
            }
    }

    unsigned short* pz = parts + (size_t)z * M * N;
    const float ds = 1.0f / 512.0f;
#pragma unroll
    for (int a = 0; a < 4; ++a) {
        const int cb = n0 + wn + a * 16 + g4 * 4;
#pragma unroll
        for (int bb = 0; bb < 4; ++bb) {
            const int r = m0 + wm + bb * 16 + m16;
            const size_t idx = (size_t)r * N + cb;
            ushort4 o = {f2bf(acc[a][bb][0] * ds), f2bf(acc[a][bb][1] * ds),
                         f2bf(acc[a][bb][2] * ds), f2bf(acc[a][bb][3] * ds)};
            *(ushort4*)(pz + idx) = o;
        }
    }
}

// ---------------------------------------------------------------------------
// Split-K reduce: out[i] = resid[i] + bias[i%N] + sum_z parts[z][i]  (fp32 out)
// ---------------------------------------------------------------------------
template <int NP>
__global__ __launch_bounds__(256) void reduce_kernel(
        const unsigned short* __restrict__ parts,
        const float* __restrict__ resid,
        const float* __restrict__ bias,
        float* __restrict__ out, int MN, int N4mask) {
    int i = blockIdx.x * 256 + threadIdx.x;
    if (i * 4 >= MN) return;
    float4 res = ((const float4*)resid)[i];
    float4 bv  = *(const float4*)(bias + (i & N4mask) * 4);
    float4 o = {res.x + bv.x, res.y + bv.y, res.z + bv.z, res.w + bv.w};
#pragma unroll
    for (int z = 0; z < NP; ++z) {
        ushort4 u = ((const ushort4*)(parts + (size_t)z * MN))[i];
        o.x += bf2f(u.x); o.y += bf2f(u.y); o.z += bf2f(u.z); o.w += bf2f(u.w);
    }
    ((float4*)out)[i] = o;
}

// ---------------------------------------------------------------------------
// V^T pre-transpose with baked PV key-permutation.
// ---------------------------------------------------------------------------
__global__ __launch_bounds__(256) void vtrans_kernel(const unsigned short* __restrict__ qkv,
                                                     unsigned short* __restrict__ vt) {
    __shared__ unsigned short Vs[64 * 64];
    const int stile = blockIdx.x;
    const int bh = blockIdx.y;
    const int b = bh >> 4, h = bh & 15;
    const int tid = threadIdx.x;
#pragma unroll
    for (int j = 0; j < 2; ++j) {
        int c = j * 256 + tid;
        int r = c >> 3, d8 = (c & 7) * 8;
        int s = stile * 64 + r;
        uint4 v = {0u, 0u, 0u, 0u};
        if (s < Sv) v = *(const uint4*)(qkv + ((size_t)(b * Sv + s) * 3 + 2) * Cv + h * 64 + d8);
        *(uint4*)&Vs[r * 64 + d8] = v;
    }
    __syncthreads();
    const int d  = tid >> 2;
    const int p0 = (tid & 3) * 16;
    unsigned short tmp[16];
#pragma unroll
    for (int e = 0; e < 16; ++e) {
        int p = p0 + e;
        int s_local = (p & 32) + 16 * ((p >> 2) & 1) + 4 * ((p & 31) >> 3) + (p & 3);
        tmp[e] = Vs[s_local * 64 + d];
    }
    unsigned short* dst = vt + ((size_t)bh * 64 + d) * SPADv + stile * 64 + p0;
    *(uint4*)dst       = *(const uint4*)&tmp[0];
    *(uint4*)(dst + 8) = *(const uint4*)&tmp[8];
}

// ---------------------------------------------------------------------------
// Flash attention, S^T formulation.
// ---------------------------------------------------------------------------
__global__ __launch_bounds__(256) void attn_kernel(const unsigned short* __restrict__ qkv,
                                                   const unsigned short* __restrict__ vt,
                                                   unsigned short* __restrict__ o) {
    __shared__ unsigned short Qs[64 * 64];
    __shared__ unsigned short Ks[2][64 * 64];
    __shared__ unsigned short Vts[2][64 * 64];

    const int tid  = threadIdx.x;
    const int lane = tid & 63;
    const int wave = tid >> 6;
    const int m16  = lane & 15;
    const int g4   = lane >> 4;
    const int qt = blockIdx.x;
    const int bh = blockIdx.y;
    const int b = bh >> 4, h = bh & 15;

    const int lr = lane >> 3;
    const int csw = ((lane & 7) ^ lr) * 8;
    const int sw7 = m16 & 7;

#pragma unroll
    for (int j = 0; j < 2; ++j) {
        int r = wave * 16 + j * 8 + lr;
        int s = Iv + qt * 64 + r;
        gload_lds16(qkv + ((size_t)(b * Sv + s) * 3) * Cv + h * 64 + csw,
                    &Qs[(wave * 16 + j * 8) * 64]);
    }

    auto stage_kv = [&](int st, int buf) {
#pragma unroll
        for (int j = 0; j < 2; ++j) {
            int r = wave * 16 + j * 8 + lr;
            int s = st * 64 + r; if (s > Sv - 1) s = Sv - 1;
            gload_lds16(qkv + ((size_t)(b * Sv + s) * 3 + 1) * Cv + h * 64 + csw,
                        &Ks[buf][(wave * 16 + j * 8) * 64]);
            gload_lds16(vt + ((size_t)bh * 64 + r) * SPADv + st * 64 + csw,
                        &Vts[buf][(wave * 16 + j * 8) * 64]);
        }
    };

    f32x4_t oacc[4];
#pragma unroll
    for (int dt = 0; dt < 4; ++dt) oacc[dt] = zero4();
    float m_run = -1e30f, l_run = 0.f;

    stage_kv(0, 0);
    __syncthreads();

    const bf16x8_t qf0 = *(const bf16x8_t*)&Qs[(wave * 16 + m16) * 64 + ((g4 ^ sw7) * 8)];
    const bf16x8_t qf1 = *(const bf16x8_t*)&Qs[(wave * 16 + m16) * 64 + (((4 + g4) ^ sw7) * 8)];

    const int NT = (Sv + 63) / 64;   // 18
    for (int st = 0; st < NT; ++st) {
        const int cur = st & 1;
        if (st + 1 < NT) stage_kv(st + 1, cur ^ 1);

        f32x4_t sc[4];
#pragma unroll
        for (int kt = 0; kt < 4; ++kt) {
            bf16x8_t k0 = *(const bf16x8_t*)&Ks[cur][(kt * 16 + m16) * 64 + ((g4 ^ sw7) * 8)];
            bf16x8_t k1 = *(const bf16x8_t*)&Ks[cur][(kt * 16 + m16) * 64 + (((4 + g4) ^ sw7) * 8)];
            f32x4_t z = zero4();
            z = __builtin_amdgcn_mfma_f32_16x16x32_bf16(k0, qf0, z, 0, 0, 0);
            z = __builtin_amdgcn_mfma_f32_16x16x32_bf16(k1, qf1, z, 0, 0, 0);
            sc[kt] = z;
        }

        float mx = -1e30f;
#pragma unroll
        for (int kt = 0; kt < 4; ++kt)
#pragma unroll
            for (int r = 0; r < 4; ++r) {
                int key = st * 64 + kt * 16 + g4 * 4 + r;
                float v = sc[kt][r] * 0.125f;
                v = (key < Sv) ? v : -1e30f;
                sc[kt][r] = v;
                mx = fmaxf(mx, v);
            }
        mx = fmaxf(mx, __shfl_xor(mx, 16));
        mx = fmaxf(mx, __shfl_xor(mx, 32));
        const float mnew  = fmaxf(m_run, mx);
        const float alpha = __expf(m_run - mnew);
        m_run = mnew;
        float sum = 0.f;
#pragma unroll
        for (int kt = 0; kt < 4; ++kt)
#pragma unroll
            for (int r = 0; r < 4; ++r) {
                float p = __expf(sc[kt][r] - mnew);
                sc[kt][r] = p;
                sum += p;
            }
        sum += __shfl_xor(sum, 16);
        sum += __shfl_xor(sum, 32);
        l_run = l_run * alpha + sum;
#pragma unroll
        for (int dt = 0; dt < 4; ++dt) oacc[dt] *= alpha;

        us8_t pu0, pu1;
#pragma unroll
        for (int j = 0; j < 8; ++j) {
            pu0[j] = f2bf(sc[(j >> 2)][j & 3]);
            pu1[j] = f2bf(sc[2 + (j >> 2)][j & 3]);
        }
        const bf16x8_t pf0 = __builtin_bit_cast(bf16x8_t, pu0);
        const bf16x8_t pf1 = __builtin_bit_cast(bf16x8_t, pu1);

#pragma unroll
        for (int dt = 0; dt < 4; ++dt) {
            bf16x8_t v0 = *(const bf16x8_t*)&Vts[cur][(dt * 16 + m16) * 64 + ((g4 ^ sw7) * 8)];
            bf16x8_t v1 = *(const bf16x8_t*)&Vts[cur][(dt * 16 + m16) * 64 + (((4 + g4) ^ sw7) * 8)];
            oacc[dt] = __builtin_amdgcn_mfma_f32_16x16x32_bf16(v0, pf0, oacc[dt], 0, 0, 0);
            oacc[dt] = __builtin_amdgcn_mfma_f32_16x16x32_bf16(v1, pf1, oacc[dt], 0, 0, 0);
        }
        __syncthreads();
    }

    const float inv = 1.0f / l_run;
    const int q = qt * 64 + wave * 16 + m16;
    const size_t row = (size_t)(b * Nv + q) * Cv + h * 64;
#pragma unroll
    for (int dt = 0; dt < 4; ++dt) {
        ushort4 o4 = {f2bf(oacc[dt][0] * inv), f2bf(oacc[dt][1] * inv),
                      f2bf(oacc[dt][2] * inv), f2bf(oacc[dt][3] * inv)};
        *(ushort4*)&o[row + dt * 16 + g4 * 4] = o4;
    }
}

// ---------------------------------------------------------------------------
// Launcher
// ---------------------------------------------------------------------------
extern "C" void kernel_launch(void* const* d_in, const int* in_sizes, int n_in,
                              void* d_out, int out_size, void* d_ws, size_t ws_size,
                              hipStream_t stream) {
    (void)in_sizes; (void)n_in; (void)out_size; (void)ws_size;
    const float* x       = (const float*)d_in[0];
    const float* instr   = (const float*)d_in[1];
    const float* norm1_w = (const float*)d_in[2];
    const float* norm1_b = (const float*)d_in[3];
    const float* qkv_w   = (const float*)d_in[4];
    const float* q_bias  = (const float*)d_in[5];
    const float* v_bias  = (const float*)d_in[6];
    const float* proj_w  = (const float*)d_in[7];
    const float* proj_b  = (const float*)d_in[8];
    const float* gamma_1 = (const float*)d_in[9];
    const float* gamma_2 = (const float*)d_in[10];
    const float* norm2_w = (const float*)d_in[11];
    const float* norm2_b = (const float*)d_in[12];
    const float* fc1_w   = (const float*)d_in[13];
    const float* fc1_b   = (const float*)d_in[14];
    const float* fc2_w   = (const float*)d_in[15];
    const float* fc2_b   = (const float*)d_in[16];
    const float* pfc1_w  = (const float*)d_in[17];
    const float* pfc1_b  = (const float*)d_in[18];
    const float* pfc2_w  = (const float*)d_in[19];
    const float* pfc2_b  = (const float*)d_in[20];
    const float* gate    = (const float*)d_in[21];
    const float* ir_ln_w = (const float*)d_in[22];
    const float* ir_ln_b = (const float*)d_in[23];
    const float* ir_l1_w = (const float*)d_in[24];
    const float* ir_l1_b = (const float*)d_in[25];
    const float* ir_l2_w = (const float*)d_in[26];
    const float* ir_l2_b = (const float*)d_in[27];
    float* out = (float*)d_out;

    char* ws = (char*)d_ws;
    size_t off = 0;
    auto alloc = [&](size_t bytes) -> char* {
        char* p = ws + off;
        off += (bytes + 255) & ~(size_t)255;
        return p;
    };
    unsigned short* w_qkv  = (unsigned short*)alloc((size_t)3 * Cv * Cv * 2);
    unsigned short* w_proj = (unsigned short*)alloc((size_t)Cv * Cv * 2);      // *g1
    unsigned char*  w_mlp1 = (unsigned char*)alloc((size_t)2 * HIDv * Cv);     // fp8: fc1|pfc1 x32
    unsigned char*  w_fc2  = (unsigned char*)alloc((size_t)Cv * HIDv);         // fp8 *g2*32
    unsigned char*  w_pfc2 = (unsigned char*)alloc((size_t)Cv * HIDv);         // fp8 *gate*32
    unsigned short* w_ir1  = (unsigned short*)alloc((size_t)Cv * IDv * 2);
    unsigned short* w_ir2  = (unsigned short*)alloc((size_t)Cv * Cv * 2);
    float*          qkvb   = (float*)alloc((size_t)3 * Cv * 4);
    float*          bfuse  = (float*)alloc((size_t)Cv * 4);
    float*          projb  = (float*)alloc((size_t)Cv * 4);
    float*          bcat   = (float*)alloc((size_t)2 * HIDv * 4);
    unsigned short* irln   = (unsigned short*)alloc((size_t)BIv * IDv * 2);
    unsigned short* h1     = (unsigned short*)alloc((size_t)BIv * Cv * 2);
    unsigned short* kvtmp  = (unsigned short*)alloc((size_t)BIv * Cv * 2);
    unsigned short* cat    = (unsigned short*)alloc((size_t)BSv * Cv * 2);      // 9.0 MB
    unsigned short* qkvbuf = (unsigned short*)alloc((size_t)BSv * 3 * Cv * 2);  // 27.1 MB
    unsigned short* obuf   = (unsigned short*)alloc((size_t)BNv * Cv * 2);
    float*          x1     = (float*)alloc((size_t)BNv * Cv * 4);
    unsigned char*  ybuf8  = (unsigned char*)alloc((size_t)BNv * Cv);           // fp8 x16
    unsigned char*  gbufA  = (unsigned char*)alloc((size_t)BNv * 2 * HIDv);     // fp8 33.6 MB
    unsigned short* fpart  = (unsigned short*)alloc((size_t)4 * BNv * Cv * 2);  // 33.6 MB
    unsigned short* vt     = (unsigned short*)gbufA;  // vt dead before fc1 writes gbufA
    unsigned short* ppart  = cat;                     // cat+qkvbuf dead after attn

    cvt8_kernel<<<22272, 256, 0, stream>>>(qkv_w, proj_w, fc1_w, fc2_w, pfc1_w, pfc2_w,
                                           ir_l1_w, ir_l2_w,
                                           w_qkv, w_proj, w_mlp1, w_fc2,
                                           w_mlp1 + (size_t)HIDv * Cv, w_pfc2,
                                           w_ir1, w_ir2,
                                           gamma_1, gamma_2, gate);

    bias_prep_kernel<<<52, 256, 0, stream>>>(q_bias, v_bias, fc2_b, pfc2_b, proj_b,
                                             fc1_b, pfc1_b,
                                             gamma_1, gamma_2, gate,
                                             qkvb, bfuse, projb, bcat);

    // instruct branch: LN -> Linear+GELU -> Linear
    ln_kernel<0><<<BIv, 256, 0, stream>>>(instr, ir_ln_w, ir_ln_b, irln,
                                          IDv, 1.0f / IDv, 1 << 28, 0, 0);
    // LN1 writes directly into cat rows b*S + I + n
    ln_kernel<0><<<BNv, 256, 0, stream>>>(x, norm1_w, norm1_b, cat,
                                          Cv, 1.0f / Cv, Nv, Sv, Iv);
    gemm_bf16_kernel<1><<<dim3(Cv / 128, (BIv + 127) / 128), 256, 0, stream>>>(
        irln, w_ir1, ir_l1_b, h1, BIv, Cv, IDv);
    gemm_bf16_kernel<0><<<dim3(Cv / 128, (BIv + 127) / 128), 256, 0, stream>>>(
        h1, w_ir2, ir_l2_b, kvtmp, BIv, Cv, Cv);
    scatter_kv_kernel<<<BIv, 256, 0, stream>>>(kvtmp, cat);

    // QKV projection over cat [BS, C] -> [BS, 3C]
    gemm_bf16_kernel<0><<<dim3(3 * Cv / 128, (BSv + 127) / 128), 256, 0, stream>>>(
        cat, w_qkv, qkvb, qkvbuf, BSv, 3 * Cv, Cv);

    // V^T pre-transpose (permuted), then attention
    vtrans_kernel<<<dim3(18, Bv * Hv), 256, 0, stream>>>(qkvbuf, vt);
    attn_kernel<<<dim3(Nv / 64, Bv * Hv), 256, 0, stream>>>(qkvbuf, vt, obuf);

    // proj split-K=4 (bf16 partials, XCD-swizzled), reduce into x1
    gemm_splitk_kernel<<<1024, 256, 0, stream>>>(
        obuf, w_proj, ppart, BNv, Cv, Cv, Cv / 4);
    reduce_kernel<4><<<(BNv * Cv / 4 + 255) / 256, 256, 0, stream>>>(
        ppart, x, projb, x1, BNv * Cv, Cv / 4 - 1);

    // LN2 -> fp8(16*y)
    ln_kernel<1><<<BNv, 256, 0, stream>>>(x1, norm2_w, norm2_b, ybuf8,
                                          Cv, 1.0f / Cv, 1 << 28, 0, 0);

    // fused fc1+pfc1 (fp8 mainloop, N=8192, XCD-swizzled 2048 blocks)
    gemm_fp8_gelu_kernel<<<2048, 256, 0, stream>>>(
        ybuf8, w_mlp1, bcat, gbufA, BNv, 2 * HIDv, Cv);

    // fc2 + pfc2 fp8 split-K (XCD-swizzled; z=0,1 -> fc2 halves; z=2,3 -> pfc2)
    gemm_fp8_splitk_kernel<<<1024, 256, 0, stream>>>(
        gbufA, w_fc2, gbufA + HIDv, w_pfc2, fpart,
        BNv, Cv, 2 * HIDv, HIDv, HIDv / 2, 2);
    // out = x1 + (g2*fc2_b + gate*pfc2_b) + sum(parts)
    reduce_kernel<4><<<(BNv * Cv / 4 + 255) / 256, 256, 0, stream>>>(
        fpart, x1, bfuse, out, BNv * Cv, Cv / 4 - 1);
}